// Round 1
// baseline (4906.318 us; speedup 1.0000x reference)
//
#include <hip/hip_runtime.h>
#include <cmath>

#define BB 4
#define LSEQ 1024
#define DIN 32
#define DM 512
#define EDIM 1024
#define NST 16
#define RANK 32
#define MTOK (BB*LSEQ)   // 4096

__device__ __forceinline__ float sigmoidf_(float x){ return 1.f/(1.f+__expf(-x)); }
__device__ __forceinline__ float softplusf_(float x){ return fmaxf(x,0.f) + log1pf(__expf(-fabsf(x))); }
__device__ __forceinline__ float siluf_(float x){ return x * sigmoidf_(x); }

// ---------------- generic fp32 tiled GEMM:  C[m,n] (+)= sum_k A[m,k]*W[n,k]  ----------------
// EPI: 0 = store, 1 = accumulate into C, 2 = +bias, 3 = softplus(x+bias)
template<int BM, int BN, int EPI>
__global__ __launch_bounds__(256) void gemm_k(const float* __restrict__ A,
    const float* __restrict__ W, const float* __restrict__ bias,
    float* __restrict__ C, int M, int N, int K, int lda, int ldw, int ldc)
{
  constexpr int BK = 16;
  constexpr int TX = BN/4;        // threads along n (each does 4 cols)
  constexpr int TY = 256/TX;      // threads along m
  constexpr int TM = BM/TY;       // rows per thread
  __shared__ float As[BK][BM];
  __shared__ float Ws[BK][BN];
  const int t = threadIdx.x;
  const int n0 = blockIdx.x*BN, m0 = blockIdx.y*BM;
  const int tx = t % TX, ty = t / TX;
  float acc[TM][4];
  #pragma unroll
  for (int i=0;i<TM;i++){ acc[i][0]=0.f;acc[i][1]=0.f;acc[i][2]=0.f;acc[i][3]=0.f; }

  for (int k0=0;k0<K;k0+=BK) {
    __syncthreads();
    for (int f=t; f<BM*4; f+=256) {           // stage A tile (BM x 16), transposed to [k][m]
      int row=f>>2, kq=f&3;
      float4 v = *(const float4*)(A + (size_t)(m0+row)*lda + (k0+kq*4));
      As[kq*4+0][row]=v.x; As[kq*4+1][row]=v.y; As[kq*4+2][row]=v.z; As[kq*4+3][row]=v.w;
    }
    for (int f=t; f<BN*4; f+=256) {           // stage W tile (BN x 16), transposed to [k][n]
      int row=f>>2, kq=f&3;
      float4 v = *(const float4*)(W + (size_t)(n0+row)*ldw + (k0+kq*4));
      Ws[kq*4+0][row]=v.x; Ws[kq*4+1][row]=v.y; Ws[kq*4+2][row]=v.z; Ws[kq*4+3][row]=v.w;
    }
    __syncthreads();
    #pragma unroll
    for (int kk=0;kk<BK;kk++) {
      float a[TM], b[4];
      #pragma unroll
      for (int j=0;j<4;j++) b[j] = Ws[kk][tx*4+j];
      #pragma unroll
      for (int i=0;i<TM;i++) a[i] = As[kk][ty*TM+i];
      #pragma unroll
      for (int i=0;i<TM;i++)
        #pragma unroll
        for (int j=0;j<4;j++) acc[i][j] = fmaf(a[i], b[j], acc[i][j]);
    }
  }
  #pragma unroll
  for (int i=0;i<TM;i++) {
    float* cp = C + (size_t)(m0+ty*TM+i)*ldc + n0 + tx*4;
    float4 r; r.x=acc[i][0]; r.y=acc[i][1]; r.z=acc[i][2]; r.w=acc[i][3];
    if constexpr (EPI==1) { float4 o = *(const float4*)cp; r.x+=o.x; r.y+=o.y; r.z+=o.z; r.w+=o.w; }
    if constexpr (EPI==2) { const float* bp = bias + n0 + tx*4;
      r.x+=bp[0]; r.y+=bp[1]; r.z+=bp[2]; r.w+=bp[3]; }
    if constexpr (EPI==3) { const float* bp = bias + n0 + tx*4;
      r.x=softplusf_(r.x+bp[0]); r.y=softplusf_(r.y+bp[1]);
      r.z=softplusf_(r.z+bp[2]); r.w=softplusf_(r.w+bp[3]); }
    *(float4*)cp = r;
  }
}

// ---------------- rmsnorm over rows of 512 ----------------
__global__ __launch_bounds__(256) void rmsnorm_k(const float* __restrict__ h,
    const float* __restrict__ nw, float* __restrict__ hn)
{
  int m = blockIdx.x, t = threadIdx.x;
  const float* row = h + (size_t)m*DM;
  float v0 = row[t], v1 = row[t+256];
  float s = v0*v0 + v1*v1;
  #pragma unroll
  for (int off=32; off>=1; off>>=1) s += __shfl_xor(s, off, 64);
  __shared__ float red[4];
  if ((t&63)==0) red[t>>6] = s;
  __syncthreads();
  float tot = red[0]+red[1]+red[2]+red[3];
  float r = rsqrtf(tot*(1.0f/512.0f) + 1e-5f);
  hn[(size_t)m*DM+t]     = v0*r*nw[t];
  hn[(size_t)m*DM+t+256] = v1*r*nw[t+256];
}

// ---------------- causal depthwise conv (K=4) + silu ----------------
__global__ __launch_bounds__(256) void conv_silu_k(const float* __restrict__ xz,
    const float* __restrict__ cw, const float* __restrict__ cb, float* __restrict__ xbc)
{
  int idx = blockIdx.x*256 + threadIdx.x;     // < MTOK*EDIM
  int e = idx & (EDIM-1);
  int m = idx >> 10;
  int l = m & (LSEQ-1);
  float4 w = *(const float4*)(cw + e*4);      // w.x=k0 .. w.w=k3
  const float* xp = xz + (size_t)m*2048 + e;  // xb half of xz
  float acc = cb[e] + w.w * xp[0];
  if (l>0) acc += w.z * xp[-2048];
  if (l>1) acc += w.y * xp[-2*2048];
  if (l>2) acc += w.x * xp[-3*2048];
  xbc[idx] = siluf_(acc);
}

// ---------------- selective scan: parallel over (b, ed), sequential over l ----------------
__global__ __launch_bounds__(256) void scan_k(const float* __restrict__ xbc,
    const float* __restrict__ delta, const float* __restrict__ dbc,
    const float* __restrict__ A_log, const float* __restrict__ Dp,
    float* __restrict__ y)
{
  int tid = blockIdx.x*256 + threadIdx.x;     // < 4096
  int ed = tid & (EDIM-1);
  int b  = tid >> 10;
  float a[NST];
  #pragma unroll
  for (int n=0;n<NST;n++) a[n] = -__expf(A_log[ed*NST+n]);
  float Dv = Dp[ed];
  float hs[NST];
  #pragma unroll
  for (int n=0;n<NST;n++) hs[n] = 0.f;
  const float* dp = delta + (size_t)b*LSEQ*EDIM + ed;
  const float* xp = xbc   + (size_t)b*LSEQ*EDIM + ed;
  const float* bc = dbc   + (size_t)b*LSEQ*64;
  float* yp = y + (size_t)b*LSEQ*EDIM + ed;
  float dt = dp[0], xv = xp[0];
  for (int l=0;l<LSEQ;l++) {
    int ln = (l+1 < LSEQ) ? l+1 : l;
    float dtn = dp[(size_t)ln*EDIM];          // prefetch next step
    float xvn = xp[(size_t)ln*EDIM];
    float dx = dt*xv;
    float yv = xv*Dv;
    const float* bcl = bc + l*64;
    #pragma unroll
    for (int n=0;n<NST;n++) {
      float dA = __expf(dt*a[n]);
      hs[n] = fmaf(dA, hs[n], dx*bcl[32+n]);  // h = dA*h + dt*x*B
      yv = fmaf(hs[n], bcl[48+n], yv);        // y += h*C
    }
    yp[(size_t)l*EDIM] = yv;
    dt = dtn; xv = xvn;
  }
}

// ---------------- y * silu(z) ----------------
__global__ __launch_bounds__(256) void yz_silu_k(const float* __restrict__ y,
    const float* __restrict__ xz, float* __restrict__ yz)
{
  int idx = blockIdx.x*256 + threadIdx.x;
  int e = idx & (EDIM-1);
  int m = idx >> 10;
  float zv = xz[(size_t)m*2048 + 1024 + e];
  yz[idx] = y[idx] * siluf_(zv);
}

// ---------------- fc2 (D=512 -> 1) + sigmoid ----------------
__global__ __launch_bounds__(64) void fc2_k(const float* __restrict__ h,
    const float* __restrict__ w, const float* __restrict__ b, float* __restrict__ out)
{
  int m = blockIdx.x, t = threadIdx.x;
  float s = 0.f;
  #pragma unroll
  for (int j=0;j<8;j++) { int k = t + j*64; s = fmaf(h[(size_t)m*DM+k], w[k], s); }
  #pragma unroll
  for (int off=32; off>=1; off>>=1) s += __shfl_xor(s, off, 64);
  if (t==0) out[m] = sigmoidf_(s + b[0]);
}

extern "C" void kernel_launch(void* const* d_in, const int* in_sizes, int n_in,
                              void* d_out, int out_size, void* d_ws, size_t ws_size,
                              hipStream_t stream) {
  const float* x         = (const float*)d_in[0];
  const float* fc1_w     = (const float*)d_in[1];
  const float* fc1_b     = (const float*)d_in[2];
  const float* fc2_w     = (const float*)d_in[3];
  const float* fc2_b     = (const float*)d_in[4];
  const float* norm_w    = (const float*)d_in[5];
  const float* in_proj_w = (const float*)d_in[6];
  const float* conv_w    = (const float*)d_in[7];
  const float* conv_b    = (const float*)d_in[8];
  const float* xproj_w   = (const float*)d_in[9];
  const float* dtproj_w  = (const float*)d_in[10];
  const float* dtproj_b  = (const float*)d_in[11];
  const float* A_log     = (const float*)d_in[12];
  const float* D_param   = (const float*)d_in[13];
  const float* out_proj_w= (const float*)d_in[14];
  float* out = (float*)d_out;

  float* ws   = (float*)d_ws;
  float* h    = ws;                  // 2097152
  float* hn   = ws + 2097152;        // 2097152
  float* xz   = ws + 4194304;        // 8388608  (xb = cols 0..1023, z = 1024..2047)
  float* xbc  = ws + 12582912;       // 4194304  (conv+silu output; reused as y*silu(z))
  float* dbcw = ws + 16777216;       // 262144   (dt | B | C)
  float* dl   = ws + 17039360;       // 4194304  (delta)
  float* yw   = ws + 21233664;       // 4194304  (scan output)

  // fc1: h = x @ fc1_w^T + fc1_b    (4096 x 512, K=32)
  gemm_k<128,64,2><<<dim3(DM/64, MTOK/128), 256, 0, stream>>>(
      x, fc1_w, fc1_b, h, MTOK, DM, DIN, DIN, DIN, DM);

  for (int i=0;i<4;i++) {
    // hn = rmsnorm(h, norm_w[i])
    rmsnorm_k<<<MTOK, 256, 0, stream>>>(h, norm_w + (size_t)i*DM, hn);
    // xz = hn @ in_proj_w^T         (4096 x 2048, K=512)
    gemm_k<128,64,0><<<dim3(2048/64, MTOK/128), 256, 0, stream>>>(
        hn, in_proj_w + (size_t)i*2048*DM, nullptr, xz, MTOK, 2048, DM, DM, DM, 2048);
    // xbc = silu(conv(xb) + conv_b)
    conv_silu_k<<<(MTOK*EDIM)/256, 256, 0, stream>>>(
        xz, conv_w + (size_t)i*EDIM*4, conv_b + (size_t)i*EDIM, xbc);
    // dbc = xbc @ xproj_w^T         (4096 x 64, K=1024)
    gemm_k<32,64,0><<<dim3(1, MTOK/32), 256, 0, stream>>>(
        xbc, xproj_w + (size_t)i*64*EDIM, nullptr, dbcw, MTOK, 64, EDIM, EDIM, EDIM, 64);
    // delta = softplus(dt @ dtproj_w^T + dtproj_b)   (4096 x 1024, K=32, lda=64)
    gemm_k<128,64,3><<<dim3(EDIM/64, MTOK/128), 256, 0, stream>>>(
        dbcw, dtproj_w + (size_t)i*EDIM*RANK, dtproj_b + (size_t)i*EDIM, dl,
        MTOK, EDIM, RANK, 64, RANK, EDIM);
    // selective scan
    scan_k<<<MTOK*0 + (BB*EDIM)/256, 256, 0, stream>>>(
        xbc, dl, dbcw, A_log + (size_t)i*EDIM*NST, D_param + (size_t)i*EDIM, yw);
    // yz = y * silu(z)   (into xbc)
    yz_silu_k<<<(MTOK*EDIM)/256, 256, 0, stream>>>(yw, xz, xbc);
    // h += yz @ out_proj_w^T        (4096 x 512, K=1024)
    gemm_k<128,64,1><<<dim3(DM/64, MTOK/128), 256, 0, stream>>>(
        xbc, out_proj_w + (size_t)i*DM*EDIM, nullptr, h, MTOK, DM, EDIM, EDIM, EDIM, DM);
  }

  // out = sigmoid(h @ fc2_w^T + fc2_b)
  fc2_k<<<MTOK, 64, 0, stream>>>(h, fc2_w, fc2_b, out);
}

// Round 2
// 1649.572 us; speedup vs baseline: 2.9743x; 2.9743x over previous
//
#include <hip/hip_runtime.h>
#include <cmath>

#define BB 4
#define LSEQ 1024
#define DIN 32
#define DM 512
#define EDIM 1024
#define NST 16
#define RANK 32
#define MTOK (BB*LSEQ)   // 4096
#define NC 32            // scan chunks
#define CH (LSEQ/NC)     // 32 steps per chunk

__device__ __forceinline__ float sigmoidf_(float x){ return 1.f/(1.f+__expf(-x)); }
__device__ __forceinline__ float softplusf_(float x){ return fmaxf(x,0.f) + log1pf(__expf(-fabsf(x))); }
__device__ __forceinline__ float siluf_(float x){ return x * sigmoidf_(x); }

// ---------------- generic fp32 tiled GEMM:  C[m,n] (+)= sum_k A[m,k]*W[n,k]  ----------------
// EPI: 0 = store, 1 = accumulate into C, 2 = +bias, 3 = softplus(x+bias)
template<int BM, int BN, int EPI>
__global__ __launch_bounds__(256) void gemm_k(const float* __restrict__ A,
    const float* __restrict__ W, const float* __restrict__ bias,
    float* __restrict__ C, int M, int N, int K, int lda, int ldw, int ldc)
{
  constexpr int BK = 16;
  constexpr int TX = BN/4;        // threads along n (each does 4 cols)
  constexpr int TY = 256/TX;      // threads along m
  constexpr int TM = BM/TY;       // rows per thread
  __shared__ float As[BK][BM];
  __shared__ float Ws[BK][BN];
  const int t = threadIdx.x;
  const int n0 = blockIdx.x*BN, m0 = blockIdx.y*BM;
  const int tx = t % TX, ty = t / TX;
  float acc[TM][4];
  #pragma unroll
  for (int i=0;i<TM;i++){ acc[i][0]=0.f;acc[i][1]=0.f;acc[i][2]=0.f;acc[i][3]=0.f; }

  for (int k0=0;k0<K;k0+=BK) {
    __syncthreads();
    for (int f=t; f<BM*4; f+=256) {           // stage A tile (BM x 16), transposed to [k][m]
      int row=f>>2, kq=f&3;
      float4 v = *(const float4*)(A + (size_t)(m0+row)*lda + (k0+kq*4));
      As[kq*4+0][row]=v.x; As[kq*4+1][row]=v.y; As[kq*4+2][row]=v.z; As[kq*4+3][row]=v.w;
    }
    for (int f=t; f<BN*4; f+=256) {           // stage W tile (BN x 16), transposed to [k][n]
      int row=f>>2, kq=f&3;
      float4 v = *(const float4*)(W + (size_t)(n0+row)*ldw + (k0+kq*4));
      Ws[kq*4+0][row]=v.x; Ws[kq*4+1][row]=v.y; Ws[kq*4+2][row]=v.z; Ws[kq*4+3][row]=v.w;
    }
    __syncthreads();
    #pragma unroll
    for (int kk=0;kk<BK;kk++) {
      float a[TM], b[4];
      #pragma unroll
      for (int j=0;j<4;j++) b[j] = Ws[kk][tx*4+j];
      #pragma unroll
      for (int i=0;i<TM;i++) a[i] = As[kk][ty*TM+i];
      #pragma unroll
      for (int i=0;i<TM;i++)
        #pragma unroll
        for (int j=0;j<4;j++) acc[i][j] = fmaf(a[i], b[j], acc[i][j]);
    }
  }
  #pragma unroll
  for (int i=0;i<TM;i++) {
    float* cp = C + (size_t)(m0+ty*TM+i)*ldc + n0 + tx*4;
    float4 r; r.x=acc[i][0]; r.y=acc[i][1]; r.z=acc[i][2]; r.w=acc[i][3];
    if constexpr (EPI==1) { float4 o = *(const float4*)cp; r.x+=o.x; r.y+=o.y; r.z+=o.z; r.w+=o.w; }
    if constexpr (EPI==2) { const float* bp = bias + n0 + tx*4;
      r.x+=bp[0]; r.y+=bp[1]; r.z+=bp[2]; r.w+=bp[3]; }
    if constexpr (EPI==3) { const float* bp = bias + n0 + tx*4;
      r.x=softplusf_(r.x+bp[0]); r.y=softplusf_(r.y+bp[1]);
      r.z=softplusf_(r.z+bp[2]); r.w=softplusf_(r.w+bp[3]); }
    *(float4*)cp = r;
  }
}

// ---------------- rmsnorm over rows of 512 ----------------
__global__ __launch_bounds__(256) void rmsnorm_k(const float* __restrict__ h,
    const float* __restrict__ nw, float* __restrict__ hn)
{
  int m = blockIdx.x, t = threadIdx.x;
  const float* row = h + (size_t)m*DM;
  float v0 = row[t], v1 = row[t+256];
  float s = v0*v0 + v1*v1;
  #pragma unroll
  for (int off=32; off>=1; off>>=1) s += __shfl_xor(s, off, 64);
  __shared__ float red[4];
  if ((t&63)==0) red[t>>6] = s;
  __syncthreads();
  float tot = red[0]+red[1]+red[2]+red[3];
  float r = rsqrtf(tot*(1.0f/512.0f) + 1e-5f);
  hn[(size_t)m*DM+t]     = v0*r*nw[t];
  hn[(size_t)m*DM+t+256] = v1*r*nw[t+256];
}

// ---------------- causal depthwise conv (K=4) + silu ----------------
__global__ __launch_bounds__(256) void conv_silu_k(const float* __restrict__ xz,
    const float* __restrict__ cw, const float* __restrict__ cb, float* __restrict__ xbc)
{
  int idx = blockIdx.x*256 + threadIdx.x;     // < MTOK*EDIM
  int e = idx & (EDIM-1);
  int m = idx >> 10;
  int l = m & (LSEQ-1);
  float4 w = *(const float4*)(cw + e*4);      // w.x=k0 .. w.w=k3
  const float* xp = xz + (size_t)m*2048 + e;  // xb half of xz
  float acc = cb[e] + w.w * xp[0];
  if (l>0) acc += w.z * xp[-2048];
  if (l>1) acc += w.y * xp[-2*2048];
  if (l>2) acc += w.x * xp[-3*2048];
  xbc[idx] = siluf_(acc);
}

// ---------------- chunked selective scan ----------------
// Layout for P/S/Hinit arrays: [b][c][n][ed]  (coalesced over ed)
// Pass A: per-chunk scan from h=0; emit P = prod(dA), S = final h.
__global__ __launch_bounds__(256) void scan_chunkA_k(const float* __restrict__ xbc,
    const float* __restrict__ delta, const float* __restrict__ dbc,
    const float* __restrict__ A_log,
    float* __restrict__ P, float* __restrict__ S)
{
  int ed = blockIdx.x*256 + threadIdx.x;      // 0..1023
  int b  = blockIdx.y;
  int c  = blockIdx.z;
  float a[NST];
  #pragma unroll
  for (int n=0;n<NST;n++) a[n] = -__expf(A_log[ed*NST+n]);
  float hs[NST], pp[NST];
  #pragma unroll
  for (int n=0;n<NST;n++){ hs[n]=0.f; pp[n]=1.f; }
  const int l0 = c*CH;
  const bool last = (c==NC-1);
  const float* dp = delta + ((size_t)b*LSEQ + l0)*EDIM + ed;
  const float* xp = xbc   + ((size_t)b*LSEQ + l0)*EDIM + ed;
  const float* bc = dbc   + ((size_t)b*LSEQ + l0)*64;
  float dt = dp[0], xv = xp[0];
  for (int l=0;l<CH;l++) {
    int ln = (l+1<CH || !last) ? l+1 : l;
    float dtn = dp[(size_t)ln*EDIM];
    float xvn = xp[(size_t)ln*EDIM];
    float dx = dt*xv;
    const float* bcl = bc + l*64;
    #pragma unroll
    for (int n=0;n<NST;n++) {
      float dA = __expf(dt*a[n]);
      hs[n] = fmaf(dA, hs[n], dx*bcl[32+n]);
      pp[n] *= dA;
    }
    dt = dtn; xv = xvn;
  }
  size_t base = (((size_t)b*NC + c)*NST)*EDIM + ed;
  #pragma unroll
  for (int n=0;n<NST;n++) { P[base + (size_t)n*EDIM] = pp[n]; S[base + (size_t)n*EDIM] = hs[n]; }
}

// Pass B: serial combine over chunks per (b,n,ed); writes chunk-initial state into PH (in place of P).
__global__ __launch_bounds__(256) void scan_combine_k(float* __restrict__ PH, const float* __restrict__ S)
{
  int t = blockIdx.x*256 + threadIdx.x;       // 0..16383 = n*EDIM+ed
  int b = blockIdx.y;
  float H = 0.f;
  for (int c=0;c<NC;c++) {
    size_t idx = (((size_t)b*NC + c)*NST)*EDIM + t;
    float p = PH[idx];
    float s = S[idx];
    PH[idx] = H;
    H = fmaf(p, H, s);
  }
}

// Pass C: replay each chunk from its true initial state, emitting y.
__global__ __launch_bounds__(256) void scan_chunkC_k(const float* __restrict__ xbc,
    const float* __restrict__ delta, const float* __restrict__ dbc,
    const float* __restrict__ A_log, const float* __restrict__ Dp,
    const float* __restrict__ Hinit, float* __restrict__ y)
{
  int ed = blockIdx.x*256 + threadIdx.x;
  int b  = blockIdx.y;
  int c  = blockIdx.z;
  float a[NST];
  #pragma unroll
  for (int n=0;n<NST;n++) a[n] = -__expf(A_log[ed*NST+n]);
  float Dv = Dp[ed];
  float hs[NST];
  size_t base = (((size_t)b*NC + c)*NST)*EDIM + ed;
  #pragma unroll
  for (int n=0;n<NST;n++) hs[n] = Hinit[base + (size_t)n*EDIM];
  const int l0 = c*CH;
  const bool last = (c==NC-1);
  const float* dp = delta + ((size_t)b*LSEQ + l0)*EDIM + ed;
  const float* xp = xbc   + ((size_t)b*LSEQ + l0)*EDIM + ed;
  const float* bc = dbc   + ((size_t)b*LSEQ + l0)*64;
  float* yp = y + ((size_t)b*LSEQ + l0)*EDIM + ed;
  float dt = dp[0], xv = xp[0];
  for (int l=0;l<CH;l++) {
    int ln = (l+1<CH || !last) ? l+1 : l;
    float dtn = dp[(size_t)ln*EDIM];
    float xvn = xp[(size_t)ln*EDIM];
    float dx = dt*xv;
    float yv = xv*Dv;
    const float* bcl = bc + l*64;
    #pragma unroll
    for (int n=0;n<NST;n++) {
      float dA = __expf(dt*a[n]);
      hs[n] = fmaf(dA, hs[n], dx*bcl[32+n]);
      yv = fmaf(hs[n], bcl[48+n], yv);
    }
    yp[(size_t)l*EDIM] = yv;
    dt = dtn; xv = xvn;
  }
}

// ---------------- y * silu(z) ----------------
__global__ __launch_bounds__(256) void yz_silu_k(const float* __restrict__ y,
    const float* __restrict__ xz, float* __restrict__ yz)
{
  int idx = blockIdx.x*256 + threadIdx.x;
  int e = idx & (EDIM-1);
  int m = idx >> 10;
  float zv = xz[(size_t)m*2048 + 1024 + e];
  yz[idx] = y[idx] * siluf_(zv);
}

// ---------------- fc2 (D=512 -> 1) + sigmoid ----------------
__global__ __launch_bounds__(64) void fc2_k(const float* __restrict__ h,
    const float* __restrict__ w, const float* __restrict__ b, float* __restrict__ out)
{
  int m = blockIdx.x, t = threadIdx.x;
  float s = 0.f;
  #pragma unroll
  for (int j=0;j<8;j++) { int k = t + j*64; s = fmaf(h[(size_t)m*DM+k], w[k], s); }
  #pragma unroll
  for (int off=32; off>=1; off>>=1) s += __shfl_xor(s, off, 64);
  if (t==0) out[m] = sigmoidf_(s + b[0]);
}

extern "C" void kernel_launch(void* const* d_in, const int* in_sizes, int n_in,
                              void* d_out, int out_size, void* d_ws, size_t ws_size,
                              hipStream_t stream) {
  const float* x         = (const float*)d_in[0];
  const float* fc1_w     = (const float*)d_in[1];
  const float* fc1_b     = (const float*)d_in[2];
  const float* fc2_w     = (const float*)d_in[3];
  const float* fc2_b     = (const float*)d_in[4];
  const float* norm_w    = (const float*)d_in[5];
  const float* in_proj_w = (const float*)d_in[6];
  const float* conv_w    = (const float*)d_in[7];
  const float* conv_b    = (const float*)d_in[8];
  const float* xproj_w   = (const float*)d_in[9];
  const float* dtproj_w  = (const float*)d_in[10];
  const float* dtproj_b  = (const float*)d_in[11];
  const float* A_log     = (const float*)d_in[12];
  const float* D_param   = (const float*)d_in[13];
  const float* out_proj_w= (const float*)d_in[14];
  float* out = (float*)d_out;

  float* ws   = (float*)d_ws;
  float* h    = ws;                  // 2097152
  float* hn   = ws + 2097152;        // 2097152 (rmsnorm out; reused as PH for scan)
  float* xz   = ws + 4194304;        // 8388608  (xb = cols 0..1023, z = 1024..2047)
  float* xbc  = ws + 12582912;       // 4194304  (conv+silu output; reused as y*silu(z))
  float* dbcw = ws + 16777216;       // 262144   (dt | B | C)
  float* dl   = ws + 17039360;       // 4194304  (delta)
  float* yw   = ws + 21233664;       // 4194304  (scan output)
  float* Send = ws + 25427968;       // 2097152  (chunk terminal states)
  float* PH   = hn;                  // 2097152  (chunk products -> chunk initial states)

  // fc1: h = x @ fc1_w^T + fc1_b    (4096 x 512, K=32)
  gemm_k<128,64,2><<<dim3(DM/64, MTOK/128), 256, 0, stream>>>(
      x, fc1_w, fc1_b, h, MTOK, DM, DIN, DIN, DIN, DM);

  for (int i=0;i<4;i++) {
    // hn = rmsnorm(h, norm_w[i])
    rmsnorm_k<<<MTOK, 256, 0, stream>>>(h, norm_w + (size_t)i*DM, hn);
    // xz = hn @ in_proj_w^T         (4096 x 2048, K=512)
    gemm_k<128,64,0><<<dim3(2048/64, MTOK/128), 256, 0, stream>>>(
        hn, in_proj_w + (size_t)i*2048*DM, nullptr, xz, MTOK, 2048, DM, DM, DM, 2048);
    // xbc = silu(conv(xb) + conv_b)
    conv_silu_k<<<(MTOK*EDIM)/256, 256, 0, stream>>>(
        xz, conv_w + (size_t)i*EDIM*4, conv_b + (size_t)i*EDIM, xbc);
    // dbc = xbc @ xproj_w^T         (4096 x 64, K=1024)
    gemm_k<32,64,0><<<dim3(1, MTOK/32), 256, 0, stream>>>(
        xbc, xproj_w + (size_t)i*64*EDIM, nullptr, dbcw, MTOK, 64, EDIM, EDIM, EDIM, 64);
    // delta = softplus(dt @ dtproj_w^T + dtproj_b)   (4096 x 1024, K=32, lda=64)
    gemm_k<128,64,3><<<dim3(EDIM/64, MTOK/128), 256, 0, stream>>>(
        dbcw, dtproj_w + (size_t)i*EDIM*RANK, dtproj_b + (size_t)i*EDIM, dl,
        MTOK, EDIM, RANK, 64, RANK, EDIM);
    // chunked selective scan: A (per-chunk), B (combine), C (replay with true init)
    scan_chunkA_k<<<dim3(EDIM/256, BB, NC), 256, 0, stream>>>(
        xbc, dl, dbcw, A_log + (size_t)i*EDIM*NST, PH, Send);
    scan_combine_k<<<dim3(NST*EDIM/256, BB), 256, 0, stream>>>(PH, Send);
    scan_chunkC_k<<<dim3(EDIM/256, BB, NC), 256, 0, stream>>>(
        xbc, dl, dbcw, A_log + (size_t)i*EDIM*NST, D_param + (size_t)i*EDIM, PH, yw);
    // yz = y * silu(z)   (into xbc)
    yz_silu_k<<<(MTOK*EDIM)/256, 256, 0, stream>>>(yw, xz, xbc);
    // h += yz @ out_proj_w^T        (4096 x 512, K=1024)
    gemm_k<128,64,1><<<dim3(DM/64, MTOK/128), 256, 0, stream>>>(
        xbc, out_proj_w + (size_t)i*DM*EDIM, nullptr, h, MTOK, DM, EDIM, EDIM, EDIM, DM);
  }

  // out = sigmoid(h @ fc2_w^T + fc2_b)
  fc2_k<<<MTOK, 64, 0, stream>>>(h, fc2_w, fc2_b, out);
}

// Round 3
// 1190.853 us; speedup vs baseline: 4.1200x; 1.3852x over previous
//
#include <hip/hip_runtime.h>
#include <hip/hip_bf16.h>
#include <cmath>

#define BB 4
#define LSEQ 1024
#define DIN 32
#define DM 512
#define EDIM 1024
#define NST 16
#define RANK 32
#define MTOK (BB*LSEQ)   // 4096
#define NC 16            // scan chunks
#define CH (LSEQ/NC)     // 64 steps per chunk

typedef __attribute__((ext_vector_type(8))) short bx8;
typedef __attribute__((ext_vector_type(4))) float fx4;
typedef __hip_bfloat16 bf;

__device__ __forceinline__ float sigmoidf_(float x){ return 1.f/(1.f+__expf(-x)); }
__device__ __forceinline__ float softplusf_(float x){ return fmaxf(x,0.f) + log1pf(__expf(-fabsf(x))); }
__device__ __forceinline__ float siluf_(float x){ return x * sigmoidf_(x); }

// ---------------- fp32 tiled GEMM (small GEMMs only):  C[m,n] (+)= sum_k A[m,k]*W[n,k] ----------------
// EPI: 0 = store, 2 = +bias, 3 = softplus(x+bias)
template<int BM, int BN, int EPI>
__global__ __launch_bounds__(256) void gemm_k(const float* __restrict__ A,
    const float* __restrict__ W, const float* __restrict__ bias,
    float* __restrict__ C, int M, int N, int K, int lda, int ldw, int ldc)
{
  constexpr int BK = 16;
  constexpr int TX = BN/4;
  constexpr int TY = 256/TX;
  constexpr int TM = BM/TY;
  __shared__ float As[BK][BM];
  __shared__ float Ws[BK][BN];
  const int t = threadIdx.x;
  const int n0 = blockIdx.x*BN, m0 = blockIdx.y*BM;
  const int tx = t % TX, ty = t / TX;
  float acc[TM][4];
  #pragma unroll
  for (int i=0;i<TM;i++){ acc[i][0]=0.f;acc[i][1]=0.f;acc[i][2]=0.f;acc[i][3]=0.f; }

  for (int k0=0;k0<K;k0+=BK) {
    __syncthreads();
    for (int f=t; f<BM*4; f+=256) {
      int row=f>>2, kq=f&3;
      float4 v = *(const float4*)(A + (size_t)(m0+row)*lda + (k0+kq*4));
      As[kq*4+0][row]=v.x; As[kq*4+1][row]=v.y; As[kq*4+2][row]=v.z; As[kq*4+3][row]=v.w;
    }
    for (int f=t; f<BN*4; f+=256) {
      int row=f>>2, kq=f&3;
      float4 v = *(const float4*)(W + (size_t)(n0+row)*ldw + (k0+kq*4));
      Ws[kq*4+0][row]=v.x; Ws[kq*4+1][row]=v.y; Ws[kq*4+2][row]=v.z; Ws[kq*4+3][row]=v.w;
    }
    __syncthreads();
    #pragma unroll
    for (int kk=0;kk<BK;kk++) {
      float a[TM], b[4];
      #pragma unroll
      for (int j=0;j<4;j++) b[j] = Ws[kk][tx*4+j];
      #pragma unroll
      for (int i=0;i<TM;i++) a[i] = As[kk][ty*TM+i];
      #pragma unroll
      for (int i=0;i<TM;i++)
        #pragma unroll
        for (int j=0;j<4;j++) acc[i][j] = fmaf(a[i], b[j], acc[i][j]);
    }
  }
  #pragma unroll
  for (int i=0;i<TM;i++) {
    float* cp = C + (size_t)(m0+ty*TM+i)*ldc + n0 + tx*4;
    float4 r; r.x=acc[i][0]; r.y=acc[i][1]; r.z=acc[i][2]; r.w=acc[i][3];
    if constexpr (EPI==2) { const float* bp = bias + n0 + tx*4;
      r.x+=bp[0]; r.y+=bp[1]; r.z+=bp[2]; r.w+=bp[3]; }
    if constexpr (EPI==3) { const float* bp = bias + n0 + tx*4;
      r.x=softplusf_(r.x+bp[0]); r.y=softplusf_(r.y+bp[1]);
      r.z=softplusf_(r.z+bp[2]); r.w=softplusf_(r.w+bp[3]); }
    *(float4*)cp = r;
  }
}

// ---------------- split-bf16 MFMA GEMM: C[m,n] (+)= sum_k A[m,k]*W[n,k], A=Ahi+Alo, W=Whi+Wlo ----------
// EPI: 0 = store, 1 = accumulate
template<int BM, int BN, int WR, int WC, int EPI>
__global__ __launch_bounds__(256) void gemm_mfma_k(
    const bf* __restrict__ Ahi, const bf* __restrict__ Alo,
    const bf* __restrict__ Whi, const bf* __restrict__ Wlo,
    float* __restrict__ C, int M, int N, int K)
{
  constexpr int BK = 32;
  constexpr int LDT = BK + 8;            // padded row stride: 20*r mod 32 covers all banks over 8 rows
  constexpr int WM = BM/WR, WN = BN/WC;
  constexpr int FM = WM/16, FN = WN/16;
  constexpr int CA = BM*4/256, CW = BN*4/256;
  __shared__ bf At[2][BM*LDT];
  __shared__ bf Wt[2][BN*LDT];
  const int t = threadIdx.x;
  const int w = t>>6, lane = t&63;
  const int wr = w%WR, wc = w/WR;
  const int lr = lane&15, lk = lane>>4;
  const int m0 = blockIdx.y*BM, n0 = blockIdx.x*BN;

  fx4 acc[FM][FN];
  #pragma unroll
  for (int i=0;i<FM;i++)
    #pragma unroll
    for (int j=0;j<FN;j++) acc[i][j] = fx4{0.f,0.f,0.f,0.f};

  for (int k0=0;k0<K;k0+=BK) {
    __syncthreads();
    #pragma unroll
    for (int q=0;q<CA;q++) {
      int c = q*256+t, row = c>>2, ko = (c&3)*8;
      size_t g = (size_t)(m0+row)*K + k0 + ko;
      float4 vh = *(const float4*)(Ahi+g);
      float4 vl = *(const float4*)(Alo+g);
      *(float4*)&At[0][row*LDT+ko] = vh;
      *(float4*)&At[1][row*LDT+ko] = vl;
    }
    #pragma unroll
    for (int q=0;q<CW;q++) {
      int c = q*256+t, row = c>>2, ko = (c&3)*8;
      size_t g = (size_t)(n0+row)*K + k0 + ko;
      float4 vh = *(const float4*)(Whi+g);
      float4 vl = *(const float4*)(Wlo+g);
      *(float4*)&Wt[0][row*LDT+ko] = vh;
      *(float4*)&Wt[1][row*LDT+ko] = vl;
    }
    __syncthreads();
    bx8 ah[FM], al[FM], bh[FN], bl[FN];
    #pragma unroll
    for (int i=0;i<FM;i++) {
      int row = wr*WM + i*16 + lr;
      ah[i] = *(const bx8*)&At[0][row*LDT + lk*8];
      al[i] = *(const bx8*)&At[1][row*LDT + lk*8];
    }
    #pragma unroll
    for (int j=0;j<FN;j++) {
      int row = wc*WN + j*16 + lr;
      bh[j] = *(const bx8*)&Wt[0][row*LDT + lk*8];
      bl[j] = *(const bx8*)&Wt[1][row*LDT + lk*8];
    }
    #pragma unroll
    for (int i=0;i<FM;i++)
      #pragma unroll
      for (int j=0;j<FN;j++) {
        acc[i][j] = __builtin_amdgcn_mfma_f32_16x16x32_bf16(ah[i], bh[j], acc[i][j], 0,0,0);
        acc[i][j] = __builtin_amdgcn_mfma_f32_16x16x32_bf16(ah[i], bl[j], acc[i][j], 0,0,0);
        acc[i][j] = __builtin_amdgcn_mfma_f32_16x16x32_bf16(al[i], bh[j], acc[i][j], 0,0,0);
      }
  }
  #pragma unroll
  for (int i=0;i<FM;i++)
    #pragma unroll
    for (int j=0;j<FN;j++) {
      int col = n0 + wc*WN + j*16 + lr;
      #pragma unroll
      for (int r=0;r<4;r++) {
        int row = m0 + wr*WM + i*16 + lk*4 + r;
        if constexpr (EPI==1) C[(size_t)row*N+col] += acc[i][j][r];
        else                  C[(size_t)row*N+col]  = acc[i][j][r];
      }
    }
}

// ---------------- fp32 -> bf16 hi/lo split (weights) ----------------
__global__ __launch_bounds__(256) void split_k(const float* __restrict__ in,
    bf* __restrict__ hi, bf* __restrict__ lo, int n4)
{
  int i = blockIdx.x*256 + threadIdx.x;
  if (i >= n4) return;
  float4 v = ((const float4*)in)[i];
  float f[4] = {v.x, v.y, v.z, v.w};
  bf hh[4], ll[4];
  #pragma unroll
  for (int j=0;j<4;j++) {
    hh[j] = __float2bfloat16(f[j]);
    ll[j] = __float2bfloat16(f[j] - __bfloat162float(hh[j]));
  }
  *(float2*)(hi + 4*(size_t)i) = *(float2*)hh;
  *(float2*)(lo + 4*(size_t)i) = *(float2*)ll;
}

// ---------------- rmsnorm over rows of 512, emits bf16 hi/lo ----------------
__global__ __launch_bounds__(256) void rmsnorm_k(const float* __restrict__ h,
    const float* __restrict__ nw, bf* __restrict__ hn_hi, bf* __restrict__ hn_lo)
{
  int m = blockIdx.x, t = threadIdx.x;
  const float* row = h + (size_t)m*DM;
  float v0 = row[t], v1 = row[t+256];
  float s = v0*v0 + v1*v1;
  #pragma unroll
  for (int off=32; off>=1; off>>=1) s += __shfl_xor(s, off, 64);
  __shared__ float red[4];
  if ((t&63)==0) red[t>>6] = s;
  __syncthreads();
  float tot = red[0]+red[1]+red[2]+red[3];
  float r = rsqrtf(tot*(1.0f/512.0f) + 1e-5f);
  float o0 = v0*r*nw[t], o1 = v1*r*nw[t+256];
  bf h0 = __float2bfloat16(o0), h1 = __float2bfloat16(o1);
  hn_hi[(size_t)m*DM+t]     = h0;
  hn_lo[(size_t)m*DM+t]     = __float2bfloat16(o0 - __bfloat162float(h0));
  hn_hi[(size_t)m*DM+t+256] = h1;
  hn_lo[(size_t)m*DM+t+256] = __float2bfloat16(o1 - __bfloat162float(h1));
}

// ---------------- causal depthwise conv (K=4) + silu ----------------
__global__ __launch_bounds__(256) void conv_silu_k(const float* __restrict__ xz,
    const float* __restrict__ cw, const float* __restrict__ cb, float* __restrict__ xbc)
{
  int idx = blockIdx.x*256 + threadIdx.x;
  int e = idx & (EDIM-1);
  int m = idx >> 10;
  int l = m & (LSEQ-1);
  float4 w = *(const float4*)(cw + e*4);
  const float* xp = xz + (size_t)m*2048 + e;
  float acc = cb[e] + w.w * xp[0];
  if (l>0) acc += w.z * xp[-2048];
  if (l>1) acc += w.y * xp[-2*2048];
  if (l>2) acc += w.x * xp[-3*2048];
  xbc[idx] = siluf_(acc);
}

// ---------------- chunked selective scan ----------------
// P/S/Hinit layout: [b][c][n][ed]
__global__ __launch_bounds__(256) void scan_chunkA_k(const float* __restrict__ xbc,
    const float* __restrict__ delta, const float* __restrict__ dbc,
    const float* __restrict__ A_log,
    float* __restrict__ P, float* __restrict__ S)
{
  int ed = blockIdx.x*256 + threadIdx.x;
  int b  = blockIdx.y;
  int c  = blockIdx.z;
  float a[NST];
  #pragma unroll
  for (int n=0;n<NST;n++) a[n] = -__expf(A_log[ed*NST+n]);
  float hs[NST], pp[NST];
  #pragma unroll
  for (int n=0;n<NST;n++){ hs[n]=0.f; pp[n]=1.f; }
  const int l0 = c*CH;
  const bool last = (c==NC-1);
  const float* dp = delta + ((size_t)b*LSEQ + l0)*EDIM + ed;
  const float* xp = xbc   + ((size_t)b*LSEQ + l0)*EDIM + ed;
  const float* bc = dbc   + ((size_t)b*LSEQ + l0)*64;
  float dt = dp[0], xv = xp[0];
  for (int l=0;l<CH;l++) {
    int ln = (l+1<CH || !last) ? l+1 : l;
    float dtn = dp[(size_t)ln*EDIM];
    float xvn = xp[(size_t)ln*EDIM];
    float dx = dt*xv;
    const float* bcl = bc + l*64;
    #pragma unroll
    for (int n=0;n<NST;n++) {
      float dA = __expf(dt*a[n]);
      hs[n] = fmaf(dA, hs[n], dx*bcl[32+n]);
      pp[n] *= dA;
    }
    dt = dtn; xv = xvn;
  }
  size_t base = (((size_t)b*NC + c)*NST)*EDIM + ed;
  #pragma unroll
  for (int n=0;n<NST;n++) { P[base + (size_t)n*EDIM] = pp[n]; S[base + (size_t)n*EDIM] = hs[n]; }
}

__global__ __launch_bounds__(256) void scan_combine_k(float* __restrict__ PH, const float* __restrict__ S)
{
  int t = blockIdx.x*256 + threadIdx.x;       // n*EDIM+ed
  int b = blockIdx.y;
  float H = 0.f;
  for (int c=0;c<NC;c++) {
    size_t idx = (((size_t)b*NC + c)*NST)*EDIM + t;
    float p = PH[idx];
    float s = S[idx];
    PH[idx] = H;
    H = fmaf(p, H, s);
  }
}

// Pass C: replay chunk from true init; fused y*silu(z) gate; emits bf16 hi/lo for out_proj.
__global__ __launch_bounds__(256) void scan_chunkC_k(const float* __restrict__ xbc,
    const float* __restrict__ delta, const float* __restrict__ dbc,
    const float* __restrict__ A_log, const float* __restrict__ Dp,
    const float* __restrict__ Hinit, const float* __restrict__ xz,
    bf* __restrict__ yz_hi, bf* __restrict__ yz_lo)
{
  int ed = blockIdx.x*256 + threadIdx.x;
  int b  = blockIdx.y;
  int c  = blockIdx.z;
  float a[NST];
  #pragma unroll
  for (int n=0;n<NST;n++) a[n] = -__expf(A_log[ed*NST+n]);
  float Dv = Dp[ed];
  float hs[NST];
  size_t base = (((size_t)b*NC + c)*NST)*EDIM + ed;
  #pragma unroll
  for (int n=0;n<NST;n++) hs[n] = Hinit[base + (size_t)n*EDIM];
  const int l0 = c*CH;
  const bool last = (c==NC-1);
  const float* dp = delta + ((size_t)b*LSEQ + l0)*EDIM + ed;
  const float* xp = xbc   + ((size_t)b*LSEQ + l0)*EDIM + ed;
  const float* bc = dbc   + ((size_t)b*LSEQ + l0)*64;
  const float* zp = xz + ((size_t)b*LSEQ + l0)*2048 + 1024 + ed;
  bf* yh = yz_hi + ((size_t)b*LSEQ + l0)*EDIM + ed;
  bf* yl = yz_lo + ((size_t)b*LSEQ + l0)*EDIM + ed;
  float dt = dp[0], xv = xp[0];
  for (int l=0;l<CH;l++) {
    int ln = (l+1<CH || !last) ? l+1 : l;
    float dtn = dp[(size_t)ln*EDIM];
    float xvn = xp[(size_t)ln*EDIM];
    float dx = dt*xv;
    float yv = xv*Dv;
    const float* bcl = bc + l*64;
    #pragma unroll
    for (int n=0;n<NST;n++) {
      float dA = __expf(dt*a[n]);
      hs[n] = fmaf(dA, hs[n], dx*bcl[32+n]);
      yv = fmaf(hs[n], bcl[48+n], yv);
    }
    float g = yv * siluf_(zp[(size_t)l*2048]);
    bf gh = __float2bfloat16(g);
    yh[(size_t)l*EDIM] = gh;
    yl[(size_t)l*EDIM] = __float2bfloat16(g - __bfloat162float(gh));
    dt = dtn; xv = xvn;
  }
}

// ---------------- fc2 (D=512 -> 1) + sigmoid ----------------
__global__ __launch_bounds__(64) void fc2_k(const float* __restrict__ h,
    const float* __restrict__ w, const float* __restrict__ b, float* __restrict__ out)
{
  int m = blockIdx.x, t = threadIdx.x;
  float s = 0.f;
  #pragma unroll
  for (int j=0;j<8;j++) { int k = t + j*64; s = fmaf(h[(size_t)m*DM+k], w[k], s); }
  #pragma unroll
  for (int off=32; off>=1; off>>=1) s += __shfl_xor(s, off, 64);
  if (t==0) out[m] = sigmoidf_(s + b[0]);
}

extern "C" void kernel_launch(void* const* d_in, const int* in_sizes, int n_in,
                              void* d_out, int out_size, void* d_ws, size_t ws_size,
                              hipStream_t stream) {
  const float* x         = (const float*)d_in[0];
  const float* fc1_w     = (const float*)d_in[1];
  const float* fc1_b     = (const float*)d_in[2];
  const float* fc2_w     = (const float*)d_in[3];
  const float* fc2_b     = (const float*)d_in[4];
  const float* norm_w    = (const float*)d_in[5];
  const float* in_proj_w = (const float*)d_in[6];
  const float* conv_w    = (const float*)d_in[7];
  const float* conv_b    = (const float*)d_in[8];
  const float* xproj_w   = (const float*)d_in[9];
  const float* dtproj_w  = (const float*)d_in[10];
  const float* dtproj_b  = (const float*)d_in[11];
  const float* A_log     = (const float*)d_in[12];
  const float* D_param   = (const float*)d_in[13];
  const float* out_proj_w= (const float*)d_in[14];
  float* out = (float*)d_out;

  char* w8 = (char*)d_ws;                      // total footprint: 103 MB
  float* h    = (float*)(w8 +   0ull*1048576); //  8 MB
  float* xz   = (float*)(w8 +   8ull*1048576); // 32 MB
  float* xbc  = (float*)(w8 +  40ull*1048576); // 16 MB
  float* dl   = (float*)(w8 +  56ull*1048576); // 16 MB
  float* dbcw = (float*)(w8 +  72ull*1048576); //  1 MB
  float* Send = (float*)(w8 +  73ull*1048576); //  4 MB
  float* PH   = (float*)(w8 +  77ull*1048576); //  4 MB
  bf* hn_hi   = (bf*)(w8 +  81ull*1048576);    //  4 MB  (union with yz_hi)
  bf* hn_lo   = (bf*)(w8 +  85ull*1048576);    //  4 MB
  bf* yz_hi   = (bf*)(w8 +  81ull*1048576);    //  8 MB  (hn dead by scan C)
  bf* yz_lo   = (bf*)(w8 +  89ull*1048576);    //  8 MB
  bf* win_hi  = (bf*)(w8 +  97ull*1048576);    //  2 MB
  bf* win_lo  = (bf*)(w8 +  99ull*1048576);    //  2 MB
  bf* wout_hi = (bf*)(w8 + 101ull*1048576);    //  1 MB
  bf* wout_lo = (bf*)(w8 + 102ull*1048576);    //  1 MB

  // fc1: h = x @ fc1_w^T + fc1_b    (4096 x 512, K=32)
  gemm_k<128,64,2><<<dim3(DM/64, MTOK/128), 256, 0, stream>>>(
      x, fc1_w, fc1_b, h, MTOK, DM, DIN, DIN, DIN, DM);

  for (int i=0;i<4;i++) {
    // hn (bf16 hi/lo) = rmsnorm(h, norm_w[i])
    rmsnorm_k<<<MTOK, 256, 0, stream>>>(h, norm_w + (size_t)i*DM, hn_hi, hn_lo);
    // split in_proj_w[i] -> bf16 hi/lo
    split_k<<<(2048*512/4)/256, 256, 0, stream>>>(
        in_proj_w + (size_t)i*2048*DM, win_hi, win_lo, 2048*512/4);
    // xz = hn @ in_proj_w^T  (4096 x 2048, K=512)  [MFMA]
    gemm_mfma_k<128,128,2,2,0><<<dim3(2048/128, MTOK/128), 256, 0, stream>>>(
        hn_hi, hn_lo, win_hi, win_lo, xz, MTOK, 2048, DM);
    // xbc = silu(conv(xb) + conv_b)
    conv_silu_k<<<(MTOK*EDIM)/256, 256, 0, stream>>>(
        xz, conv_w + (size_t)i*EDIM*4, conv_b + (size_t)i*EDIM, xbc);
    // dbc = xbc @ xproj_w^T   (4096 x 64, K=1024)
    gemm_k<32,64,0><<<dim3(1, MTOK/32), 256, 0, stream>>>(
        xbc, xproj_w + (size_t)i*64*EDIM, nullptr, dbcw, MTOK, 64, EDIM, EDIM, EDIM, 64);
    // delta = softplus(dt @ dtproj_w^T + dtproj_b)   (4096 x 1024, K=32, lda=64)
    gemm_k<128,64,3><<<dim3(EDIM/64, MTOK/128), 256, 0, stream>>>(
        dbcw, dtproj_w + (size_t)i*EDIM*RANK, dtproj_b + (size_t)i*EDIM, dl,
        MTOK, EDIM, RANK, 64, RANK, EDIM);
    // chunked selective scan; pass C fuses y*silu(z) and emits bf16 hi/lo
    scan_chunkA_k<<<dim3(EDIM/256, BB, NC), 256, 0, stream>>>(
        xbc, dl, dbcw, A_log + (size_t)i*EDIM*NST, PH, Send);
    scan_combine_k<<<dim3(NST*EDIM/256, BB), 256, 0, stream>>>(PH, Send);
    scan_chunkC_k<<<dim3(EDIM/256, BB, NC), 256, 0, stream>>>(
        xbc, dl, dbcw, A_log + (size_t)i*EDIM*NST, D_param + (size_t)i*EDIM, PH,
        xz, yz_hi, yz_lo);
    // split out_proj_w[i] -> bf16 hi/lo
    split_k<<<(512*1024/4)/256, 256, 0, stream>>>(
        out_proj_w + (size_t)i*DM*EDIM, wout_hi, wout_lo, 512*1024/4);
    // h += yz @ out_proj_w^T  (4096 x 512, K=1024)  [MFMA, accumulate]
    gemm_mfma_k<128,64,4,1,1><<<dim3(512/64, MTOK/128), 256, 0, stream>>>(
        yz_hi, yz_lo, wout_hi, wout_lo, h, MTOK, DM, EDIM);
  }

  // out = sigmoid(h @ fc2_w^T + fc2_b)
  fc2_k<<<MTOK, 64, 0, stream>>>(h, fc2_w, fc2_b, out);
}

// Round 5
// 1064.999 us; speedup vs baseline: 4.6069x; 1.1182x over previous
//
#include <hip/hip_runtime.h>
#include <hip/hip_bf16.h>
#include <cmath>

#define BB 4
#define LSEQ 1024
#define DIN 32
#define DM 512
#define EDIM 1024
#define NST 16
#define RANK 32
#define MTOK (BB*LSEQ)   // 4096
#define NC 32            // scan chunks
#define CH (LSEQ/NC)     // 32 steps per chunk
#define MB 1048576ull

typedef __attribute__((ext_vector_type(8))) short bx8;
typedef __attribute__((ext_vector_type(4))) float fx4;
typedef __hip_bfloat16 bf;

__device__ __forceinline__ float sigmoidf_(float x){ return 1.f/(1.f+__expf(-x)); }
__device__ __forceinline__ float softplusf_(float x){ return fmaxf(x,0.f) + log1pf(__expf(-fabsf(x))); }
__device__ __forceinline__ float siluf_(float x){ return x * sigmoidf_(x); }

// ---------------- fp32 tiled GEMM (fc1, dtproj):  C[m,n] = sum_k A[m,k]*W[n,k] ----------------
// EPI: 0 = store, 2 = +bias, 3 = softplus(x+bias)
template<int BM, int BN, int EPI>
__global__ __launch_bounds__(256) void gemm_k(const float* __restrict__ A,
    const float* __restrict__ W, const float* __restrict__ bias,
    float* __restrict__ C, int M, int N, int K, int lda, int ldw, int ldc)
{
  constexpr int BK = 16;
  constexpr int TX = BN/4;
  constexpr int TY = 256/TX;
  constexpr int TM = BM/TY;
  __shared__ float As[BK][BM];
  __shared__ float Ws[BK][BN];
  const int t = threadIdx.x;
  const int n0 = blockIdx.x*BN, m0 = blockIdx.y*BM;
  const int tx = t % TX, ty = t / TX;
  float acc[TM][4];
  #pragma unroll
  for (int i=0;i<TM;i++){ acc[i][0]=0.f;acc[i][1]=0.f;acc[i][2]=0.f;acc[i][3]=0.f; }

  for (int k0=0;k0<K;k0+=BK) {
    __syncthreads();
    for (int f=t; f<BM*4; f+=256) {
      int row=f>>2, kq=f&3;
      float4 v = *(const float4*)(A + (size_t)(m0+row)*lda + (k0+kq*4));
      As[kq*4+0][row]=v.x; As[kq*4+1][row]=v.y; As[kq*4+2][row]=v.z; As[kq*4+3][row]=v.w;
    }
    for (int f=t; f<BN*4; f+=256) {
      int row=f>>2, kq=f&3;
      float4 v = *(const float4*)(W + (size_t)(n0+row)*ldw + (k0+kq*4));
      Ws[kq*4+0][row]=v.x; Ws[kq*4+1][row]=v.y; Ws[kq*4+2][row]=v.z; Ws[kq*4+3][row]=v.w;
    }
    __syncthreads();
    #pragma unroll
    for (int kk=0;kk<BK;kk++) {
      float a[TM], b[4];
      #pragma unroll
      for (int j=0;j<4;j++) b[j] = Ws[kk][tx*4+j];
      #pragma unroll
      for (int i=0;i<TM;i++) a[i] = As[kk][ty*TM+i];
      #pragma unroll
      for (int i=0;i<TM;i++)
        #pragma unroll
        for (int j=0;j<4;j++) acc[i][j] = fmaf(a[i], b[j], acc[i][j]);
    }
  }
  #pragma unroll
  for (int i=0;i<TM;i++) {
    float* cp = C + (size_t)(m0+ty*TM+i)*ldc + n0 + tx*4;
    float4 r; r.x=acc[i][0]; r.y=acc[i][1]; r.z=acc[i][2]; r.w=acc[i][3];
    if constexpr (EPI==2) { const float* bp = bias + n0 + tx*4;
      r.x+=bp[0]; r.y+=bp[1]; r.z+=bp[2]; r.w+=bp[3]; }
    if constexpr (EPI==3) { const float* bp = bias + n0 + tx*4;
      r.x=softplusf_(r.x+bp[0]); r.y=softplusf_(r.y+bp[1]);
      r.z=softplusf_(r.z+bp[2]); r.w=softplusf_(r.w+bp[3]); }
    *(float4*)cp = r;
  }
}

// ---------------- split-bf16 MFMA GEMM: C[m,n] (+)= sum_k A[m,k]*W[n,k] ----------
// EPI: 0 = store, 1 = accumulate
template<int BM, int BN, int WR, int WC, int EPI>
__global__ __launch_bounds__(256) void gemm_mfma_k(
    const bf* __restrict__ Ahi, const bf* __restrict__ Alo,
    const bf* __restrict__ Whi, const bf* __restrict__ Wlo,
    float* __restrict__ C, int M, int N, int K)
{
  constexpr int BK = 32;
  constexpr int LDT = BK + 8;
  constexpr int WM = BM/WR, WN = BN/WC;
  constexpr int FM = WM/16, FN = WN/16;
  constexpr int CA = BM*4/256, CW = BN*4/256;
  __shared__ bf At[2][BM*LDT];
  __shared__ bf Wt[2][BN*LDT];
  const int t = threadIdx.x;
  const int w = t>>6, lane = t&63;
  const int wr = w%WR, wc = w/WR;
  const int lr = lane&15, lk = lane>>4;
  const int m0 = blockIdx.y*BM, n0 = blockIdx.x*BN;

  fx4 acc[FM][FN];
  #pragma unroll
  for (int i=0;i<FM;i++)
    #pragma unroll
    for (int j=0;j<FN;j++) acc[i][j] = fx4{0.f,0.f,0.f,0.f};

  for (int k0=0;k0<K;k0+=BK) {
    __syncthreads();
    #pragma unroll
    for (int q=0;q<CA;q++) {
      int c = q*256+t, row = c>>2, ko = (c&3)*8;
      size_t g = (size_t)(m0+row)*K + k0 + ko;
      float4 vh = *(const float4*)(Ahi+g);
      float4 vl = *(const float4*)(Alo+g);
      *(float4*)&At[0][row*LDT+ko] = vh;
      *(float4*)&At[1][row*LDT+ko] = vl;
    }
    #pragma unroll
    for (int q=0;q<CW;q++) {
      int c = q*256+t, row = c>>2, ko = (c&3)*8;
      size_t g = (size_t)(n0+row)*K + k0 + ko;
      float4 vh = *(const float4*)(Whi+g);
      float4 vl = *(const float4*)(Wlo+g);
      *(float4*)&Wt[0][row*LDT+ko] = vh;
      *(float4*)&Wt[1][row*LDT+ko] = vl;
    }
    __syncthreads();
    bx8 ah[FM], al[FM], bh[FN], bl[FN];
    #pragma unroll
    for (int i=0;i<FM;i++) {
      int row = wr*WM + i*16 + lr;
      ah[i] = *(const bx8*)&At[0][row*LDT + lk*8];
      al[i] = *(const bx8*)&At[1][row*LDT + lk*8];
    }
    #pragma unroll
    for (int j=0;j<FN;j++) {
      int row = wc*WN + j*16 + lr;
      bh[j] = *(const bx8*)&Wt[0][row*LDT + lk*8];
      bl[j] = *(const bx8*)&Wt[1][row*LDT + lk*8];
    }
    #pragma unroll
    for (int i=0;i<FM;i++)
      #pragma unroll
      for (int j=0;j<FN;j++) {
        acc[i][j] = __builtin_amdgcn_mfma_f32_16x16x32_bf16(ah[i], bh[j], acc[i][j], 0,0,0);
        acc[i][j] = __builtin_amdgcn_mfma_f32_16x16x32_bf16(ah[i], bl[j], acc[i][j], 0,0,0);
        acc[i][j] = __builtin_amdgcn_mfma_f32_16x16x32_bf16(al[i], bh[j], acc[i][j], 0,0,0);
      }
  }
  #pragma unroll
  for (int i=0;i<FM;i++)
    #pragma unroll
    for (int j=0;j<FN;j++) {
      int col = n0 + wc*WN + j*16 + lr;
      #pragma unroll
      for (int r=0;r<4;r++) {
        int row = m0 + wr*WM + i*16 + lk*4 + r;
        if constexpr (EPI==1) C[(size_t)row*N+col] += acc[i][j][r];
        else                  C[(size_t)row*N+col]  = acc[i][j][r];
      }
    }
}

// ---------------- fp32 -> bf16 hi/lo split ----------------
__global__ __launch_bounds__(256) void split_k(const float* __restrict__ in,
    bf* __restrict__ hi, bf* __restrict__ lo, int n4)
{
  int i = blockIdx.x*256 + threadIdx.x;
  if (i >= n4) return;
  float4 v = ((const float4*)in)[i];
  float f[4] = {v.x, v.y, v.z, v.w};
  bf hh[4], ll[4];
  #pragma unroll
  for (int j=0;j<4;j++) {
    hh[j] = __float2bfloat16(f[j]);
    ll[j] = __float2bfloat16(f[j] - __bfloat162float(hh[j]));
  }
  *(float2*)(hi + 4*(size_t)i) = *(float2*)hh;
  *(float2*)(lo + 4*(size_t)i) = *(float2*)ll;
}

// ---------------- rmsnorm over rows of 512, emits bf16 hi/lo ----------------
__global__ __launch_bounds__(256) void rmsnorm_k(const float* __restrict__ h,
    const float* __restrict__ nw, bf* __restrict__ hn_hi, bf* __restrict__ hn_lo)
{
  int m = blockIdx.x, t = threadIdx.x;
  const float* row = h + (size_t)m*DM;
  float v0 = row[t], v1 = row[t+256];
  float s = v0*v0 + v1*v1;
  #pragma unroll
  for (int off=32; off>=1; off>>=1) s += __shfl_xor(s, off, 64);
  __shared__ float red[4];
  if ((t&63)==0) red[t>>6] = s;
  __syncthreads();
  float tot = red[0]+red[1]+red[2]+red[3];
  float r = rsqrtf(tot*(1.0f/512.0f) + 1e-5f);
  float o0 = v0*r*nw[t], o1 = v1*r*nw[t+256];
  bf h0 = __float2bfloat16(o0), h1 = __float2bfloat16(o1);
  hn_hi[(size_t)m*DM+t]     = h0;
  hn_lo[(size_t)m*DM+t]     = __float2bfloat16(o0 - __bfloat162float(h0));
  hn_hi[(size_t)m*DM+t+256] = h1;
  hn_lo[(size_t)m*DM+t+256] = __float2bfloat16(o1 - __bfloat162float(h1));
}

// ---------------- causal depthwise conv (K=4) + silu; reads contiguous Xb ----------------
__global__ __launch_bounds__(256) void conv_silu_k(const float* __restrict__ Xb,
    const float* __restrict__ cw, const float* __restrict__ cb, float* __restrict__ xbc)
{
  int idx = blockIdx.x*256 + threadIdx.x;
  int e = idx & (EDIM-1);
  int m = idx >> 10;
  int l = m & (LSEQ-1);
  float4 w = *(const float4*)(cw + e*4);
  const float* xp = Xb + (size_t)m*EDIM + e;
  float acc = cb[e] + w.w * xp[0];
  if (l>0) acc += w.z * xp[-EDIM];
  if (l>1) acc += w.y * xp[-2*EDIM];
  if (l>2) acc += w.x * xp[-3*EDIM];
  xbc[idx] = siluf_(acc);
}

// ---------------- xproj: transpose W (64x1024 -> 1024x64) ----------------
__global__ __launch_bounds__(256) void wtrans_k(const float* __restrict__ W, float* __restrict__ Wt)
{
  __shared__ float tile[64][65];
  int kb = blockIdx.x;   // 16 k-tiles of 64
  for (int i=threadIdx.x; i<4096; i+=256) {
    int n = i>>6, c = i&63;
    tile[n][c] = W[(size_t)n*EDIM + kb*64 + c];
  }
  __syncthreads();
  for (int i=threadIdx.x; i<4096; i+=256) {
    int kk = i>>6, n = i&63;
    Wt[((size_t)kb*64+kk)*64 + n] = tile[n][kk];
  }
}

// ---------------- xproj: C[4096][64] = xbc[4096][1024] @ Wt[1024][64] ----------------
__global__ __launch_bounds__(256) void xproj_k(const float* __restrict__ A,
    const float* __restrict__ Wt, float* __restrict__ C)
{
  int m  = blockIdx.x*16 + (threadIdx.x>>4);
  int n0 = (threadIdx.x&15)*4;
  const float* ap = A + (size_t)m*EDIM;
  const float* wp = Wt + n0;
  float4 acc = {0.f,0.f,0.f,0.f};
  #pragma unroll 8
  for (int k=0;k<EDIM;k++) {
    float a = ap[k];
    float4 w = *(const float4*)(wp + (size_t)k*64);
    acc.x = fmaf(a,w.x,acc.x); acc.y = fmaf(a,w.y,acc.y);
    acc.z = fmaf(a,w.z,acc.z); acc.w = fmaf(a,w.w,acc.w);
  }
  *(float4*)(C + (size_t)m*64 + n0) = acc;
}

// ---------------- chunked selective scan (NC=32, CH=32), full register preload ----------------
// P/S/Hinit layout: [b][c][n][ed]
__global__ __launch_bounds__(256,2) void scan_chunkA_k(const float* __restrict__ xbc,
    const float* __restrict__ dl, const float* __restrict__ dbc,
    const float* __restrict__ A_log,
    float* __restrict__ P, float* __restrict__ S)
{
  int ed = blockIdx.x*256 + threadIdx.x;
  int b = blockIdx.y, c = blockIdx.z;
  const int l0 = c*CH;
  __shared__ float Bs[CH][NST];
  for (int i=threadIdx.x; i<CH*NST; i+=256) {
    int row = i>>4, col = i&15;
    Bs[row][col] = dbc[((size_t)b*LSEQ + l0 + row)*64 + 32 + col];
  }
  __syncthreads();
  const float* dp = dl  + ((size_t)b*LSEQ + l0)*EDIM + ed;
  const float* xp = xbc + ((size_t)b*LSEQ + l0)*EDIM + ed;
  float dt[CH], xv[CH];
  #pragma unroll
  for (int l=0;l<CH;l++){ dt[l]=dp[(size_t)l*EDIM]; xv[l]=xp[(size_t)l*EDIM]; }
  float a[NST], hs[NST], pp[NST];
  #pragma unroll
  for (int n=0;n<NST;n++){ a[n] = -__expf(A_log[ed*NST+n]); hs[n]=0.f; pp[n]=1.f; }
  #pragma unroll
  for (int l=0;l<CH;l++) {
    float dx = dt[l]*xv[l];
    #pragma unroll
    for (int n=0;n<NST;n++) {
      float dA = __expf(dt[l]*a[n]);
      hs[n] = fmaf(dA, hs[n], dx*Bs[l][n]);
      pp[n] *= dA;
    }
  }
  size_t base = (((size_t)b*NC + c)*NST)*EDIM + ed;
  #pragma unroll
  for (int n=0;n<NST;n++) { P[base + (size_t)n*EDIM] = pp[n]; S[base + (size_t)n*EDIM] = hs[n]; }
}

__global__ __launch_bounds__(256) void scan_combine_k(float* __restrict__ PH, const float* __restrict__ S)
{
  int t = blockIdx.x*256 + threadIdx.x;       // n*EDIM+ed
  int b = blockIdx.y;
  const size_t stride = (size_t)NST*EDIM;
  size_t b0 = (size_t)b*NC*stride + t;
  float p[NC], s[NC];
  #pragma unroll
  for (int c=0;c<NC;c++){ p[c]=PH[b0+(size_t)c*stride]; s[c]=S[b0+(size_t)c*stride]; }
  float H = 0.f;
  #pragma unroll
  for (int c=0;c<NC;c++){ PH[b0+(size_t)c*stride] = H; H = fmaf(p[c], H, s[c]); }
}

// Pass C: replay from true init; fused y*silu(z); emits bf16 hi/lo.
__global__ __launch_bounds__(256,2) void scan_chunkC_k(const float* __restrict__ xbc,
    const float* __restrict__ dl, const float* __restrict__ dbc,
    const float* __restrict__ A_log, const float* __restrict__ Dp,
    const float* __restrict__ Hinit, const float* __restrict__ Z,
    bf* __restrict__ yz_hi, bf* __restrict__ yz_lo)
{
  int ed = blockIdx.x*256 + threadIdx.x;
  int b = blockIdx.y, c = blockIdx.z;
  const int l0 = c*CH;
  __shared__ float BCs[CH][32];
  for (int i=threadIdx.x; i<CH*32; i+=256) {
    int row = i>>5, col = i&31;
    BCs[row][col] = dbc[((size_t)b*LSEQ + l0 + row)*64 + 32 + col];
  }
  __syncthreads();
  const float* dp = dl  + ((size_t)b*LSEQ + l0)*EDIM + ed;
  const float* xp = xbc + ((size_t)b*LSEQ + l0)*EDIM + ed;
  const float* zp = Z   + ((size_t)b*LSEQ + l0)*EDIM + ed;
  float dt[CH], xv[CH], zv[CH];
  #pragma unroll
  for (int l=0;l<CH;l++){ dt[l]=dp[(size_t)l*EDIM]; xv[l]=xp[(size_t)l*EDIM]; zv[l]=zp[(size_t)l*EDIM]; }
  float a[NST], hs[NST];
  size_t base = (((size_t)b*NC + c)*NST)*EDIM + ed;
  #pragma unroll
  for (int n=0;n<NST;n++){ a[n] = -__expf(A_log[ed*NST+n]); hs[n] = Hinit[base + (size_t)n*EDIM]; }
  float Dv = Dp[ed];
  bf* yh = yz_hi + ((size_t)b*LSEQ + l0)*EDIM + ed;
  bf* yl = yz_lo + ((size_t)b*LSEQ + l0)*EDIM + ed;
  #pragma unroll
  for (int l=0;l<CH;l++) {
    float dx = dt[l]*xv[l];
    float yv = xv[l]*Dv;
    #pragma unroll
    for (int n=0;n<NST;n++) {
      float dA = __expf(dt[l]*a[n]);
      hs[n] = fmaf(dA, hs[n], dx*BCs[l][n]);
      yv = fmaf(hs[n], BCs[l][16+n], yv);
    }
    float g = yv * siluf_(zv[l]);
    bf gh = __float2bfloat16(g);
    yh[(size_t)l*EDIM] = gh;
    yl[(size_t)l*EDIM] = __float2bfloat16(g - __bfloat162float(gh));
  }
}

// ---------------- fc2 (D=512 -> 1) + sigmoid ----------------
__global__ __launch_bounds__(64) void fc2_k(const float* __restrict__ h,
    const float* __restrict__ w, const float* __restrict__ b, float* __restrict__ out)
{
  int m = blockIdx.x, t = threadIdx.x;
  float s = 0.f;
  #pragma unroll
  for (int j=0;j<8;j++) { int k = t + j*64; s = fmaf(h[(size_t)m*DM+k], w[k], s); }
  #pragma unroll
  for (int off=32; off>=1; off>>=1) s += __shfl_xor(s, off, 64);
  if (t==0) out[m] = sigmoidf_(s + b[0]);
}

extern "C" void kernel_launch(void* const* d_in, const int* in_sizes, int n_in,
                              void* d_out, int out_size, void* d_ws, size_t ws_size,
                              hipStream_t stream) {
  const float* x         = (const float*)d_in[0];
  const float* fc1_w     = (const float*)d_in[1];
  const float* fc1_b     = (const float*)d_in[2];
  const float* fc2_w     = (const float*)d_in[3];
  const float* fc2_b     = (const float*)d_in[4];
  const float* norm_w    = (const float*)d_in[5];
  const float* in_proj_w = (const float*)d_in[6];
  const float* conv_w    = (const float*)d_in[7];
  const float* conv_b    = (const float*)d_in[8];
  const float* xproj_w   = (const float*)d_in[9];
  const float* dtproj_w  = (const float*)d_in[10];
  const float* dtproj_b  = (const float*)d_in[11];
  const float* A_log     = (const float*)d_in[12];
  const float* D_param   = (const float*)d_in[13];
  const float* out_proj_w= (const float*)d_in[14];
  float* out = (float*)d_out;

  char* w8 = (char*)d_ws;                  // total footprint: 103 MB
  float* h    = (float*)(w8 +  0*MB);      //  8 MB
  float* Xb   = (float*)(w8 +  8*MB);      // 16 MB (dead after conv)
  float* PH   = (float*)(w8 +  8*MB);      //  8 MB (alias Xb; live scanA..scanC)
  float* Z    = (float*)(w8 + 24*MB);      // 16 MB (live till scanC)
  float* xbc  = (float*)(w8 + 40*MB);      // 16 MB
  float* dl   = (float*)(w8 + 56*MB);      // 16 MB
  float* dbcw = (float*)(w8 + 72*MB);      //  1 MB
  bf*    win_hi = (bf*)(w8 + 73*MB);       //  2 MB (dead after in_proj)
  float* Wt     = (float*)(w8 + 73*MB);    //  256 KB (alias win; live wtrans..xproj)
  bf*    win_lo = (bf*)(w8 + 75*MB);       //  2 MB
  bf*    wout_hi= (bf*)(w8 + 77*MB);       //  1 MB
  bf*    wout_lo= (bf*)(w8 + 78*MB);       //  1 MB
  bf*    hn_hi  = (bf*)(w8 + 79*MB);       //  4 MB (dead after in_proj)
  bf*    hn_lo  = (bf*)(w8 + 83*MB);       //  4 MB
  float* Send   = (float*)(w8 + 79*MB);    //  8 MB (alias hn; live scanA..combine)
  bf*    yz_hi  = (bf*)(w8 + 87*MB);       //  8 MB
  bf*    yz_lo  = (bf*)(w8 + 95*MB);       //  8 MB

  // fc1: h = x @ fc1_w^T + fc1_b    (4096 x 512, K=32)
  gemm_k<128,64,2><<<dim3(DM/64, MTOK/128), 256, 0, stream>>>(
      x, fc1_w, fc1_b, h, MTOK, DM, DIN, DIN, DIN, DM);

  for (int i=0;i<4;i++) {
    rmsnorm_k<<<MTOK, 256, 0, stream>>>(h, norm_w + (size_t)i*DM, hn_hi, hn_lo);
    split_k<<<(2048*512/4)/256, 256, 0, stream>>>(
        in_proj_w + (size_t)i*2048*DM, win_hi, win_lo, 2048*512/4);
    // in_proj as two N=1024 MFMA GEMMs -> Xb, Z
    gemm_mfma_k<128,128,2,2,0><<<dim3(EDIM/128, MTOK/128), 256, 0, stream>>>(
        hn_hi, hn_lo, win_hi, win_lo, Xb, MTOK, EDIM, DM);
    gemm_mfma_k<128,128,2,2,0><<<dim3(EDIM/128, MTOK/128), 256, 0, stream>>>(
        hn_hi, hn_lo, win_hi + (size_t)EDIM*DM, win_lo + (size_t)EDIM*DM, Z, MTOK, EDIM, DM);
    conv_silu_k<<<(MTOK*EDIM)/256, 256, 0, stream>>>(
        Xb, conv_w + (size_t)i*EDIM*4, conv_b + (size_t)i*EDIM, xbc);
    // xproj: transpose weight then direct GEMM (4096x64, K=1024)
    wtrans_k<<<16, 256, 0, stream>>>(xproj_w + (size_t)i*64*EDIM, Wt);
    xproj_k<<<MTOK/16, 256, 0, stream>>>(xbc, Wt, dbcw);
    // delta = softplus(dt @ dtproj_w^T + dtproj_b)   (4096 x 1024, K=32, lda=64)
    gemm_k<128,64,3><<<dim3(EDIM/64, MTOK/128), 256, 0, stream>>>(
        dbcw, dtproj_w + (size_t)i*EDIM*RANK, dtproj_b + (size_t)i*EDIM, dl,
        MTOK, EDIM, RANK, 64, RANK, EDIM);
    // chunked selective scan
    scan_chunkA_k<<<dim3(EDIM/256, BB, NC), 256, 0, stream>>>(
        xbc, dl, dbcw, A_log + (size_t)i*EDIM*NST, PH, Send);
    scan_combine_k<<<dim3(NST*EDIM/256, BB), 256, 0, stream>>>(PH, Send);
    scan_chunkC_k<<<dim3(EDIM/256, BB, NC), 256, 0, stream>>>(
        xbc, dl, dbcw, A_log + (size_t)i*EDIM*NST, D_param + (size_t)i*EDIM, PH,
        Z, yz_hi, yz_lo);
    split_k<<<(512*1024/4)/256, 256, 0, stream>>>(
        out_proj_w + (size_t)i*DM*EDIM, wout_hi, wout_lo, 512*1024/4);
    // h += yz @ out_proj_w^T  (4096 x 512, K=1024)  [MFMA, accumulate]
    gemm_mfma_k<128,64,4,1,1><<<dim3(DM/64, MTOK/128), 256, 0, stream>>>(
        yz_hi, yz_lo, wout_hi, wout_lo, h, MTOK, DM, EDIM);
  }

  // out = sigmoid(h @ fc2_w^T + fc2_b)
  fc2_k<<<MTOK, 64, 0, stream>>>(h, fc2_w, fc2_b, out);
}

// Round 6
// 1036.273 us; speedup vs baseline: 4.7346x; 1.0277x over previous
//
#include <hip/hip_runtime.h>
#include <hip/hip_bf16.h>
#include <cmath>

#define BB 4
#define LSEQ 1024
#define DIN 32
#define DM 512
#define EDIM 1024
#define NST 16
#define RANK 32
#define MTOK (BB*LSEQ)   // 4096
#define NC 32            // scan chunks
#define CH (LSEQ/NC)     // 32 steps per chunk
#define MB 1048576ull

typedef __attribute__((ext_vector_type(8))) short bx8;
typedef __attribute__((ext_vector_type(4))) float fx4;
typedef __hip_bfloat16 bf;

__device__ __forceinline__ float sigmoidf_(float x){ return 1.f/(1.f+__expf(-x)); }
__device__ __forceinline__ float softplusf_(float x){ return fmaxf(x,0.f) + log1pf(__expf(-fabsf(x))); }
__device__ __forceinline__ float siluf_(float x){ return x * sigmoidf_(x); }

// ---------------- fp32 tiled GEMM (fc1, dtproj):  C[m,n] = sum_k A[m,k]*W[n,k] ----------------
// EPI: 0 = store, 2 = +bias, 3 = softplus(x+bias)
template<int BM, int BN, int EPI>
__global__ __launch_bounds__(256) void gemm_k(const float* __restrict__ A,
    const float* __restrict__ W, const float* __restrict__ bias,
    float* __restrict__ C, int M, int N, int K, int lda, int ldw, int ldc)
{
  constexpr int BK = 16;
  constexpr int TX = BN/4;
  constexpr int TY = 256/TX;
  constexpr int TM = BM/TY;
  __shared__ float As[BK][BM];
  __shared__ float Ws[BK][BN];
  const int t = threadIdx.x;
  const int n0 = blockIdx.x*BN, m0 = blockIdx.y*BM;
  const int tx = t % TX, ty = t / TX;
  float acc[TM][4];
  #pragma unroll
  for (int i=0;i<TM;i++){ acc[i][0]=0.f;acc[i][1]=0.f;acc[i][2]=0.f;acc[i][3]=0.f; }

  for (int k0=0;k0<K;k0+=BK) {
    __syncthreads();
    for (int f=t; f<BM*4; f+=256) {
      int row=f>>2, kq=f&3;
      float4 v = *(const float4*)(A + (size_t)(m0+row)*lda + (k0+kq*4));
      As[kq*4+0][row]=v.x; As[kq*4+1][row]=v.y; As[kq*4+2][row]=v.z; As[kq*4+3][row]=v.w;
    }
    for (int f=t; f<BN*4; f+=256) {
      int row=f>>2, kq=f&3;
      float4 v = *(const float4*)(W + (size_t)(n0+row)*ldw + (k0+kq*4));
      Ws[kq*4+0][row]=v.x; Ws[kq*4+1][row]=v.y; Ws[kq*4+2][row]=v.z; Ws[kq*4+3][row]=v.w;
    }
    __syncthreads();
    #pragma unroll
    for (int kk=0;kk<BK;kk++) {
      float a[TM], b[4];
      #pragma unroll
      for (int j=0;j<4;j++) b[j] = Ws[kk][tx*4+j];
      #pragma unroll
      for (int i=0;i<TM;i++) a[i] = As[kk][ty*TM+i];
      #pragma unroll
      for (int i=0;i<TM;i++)
        #pragma unroll
        for (int j=0;j<4;j++) acc[i][j] = fmaf(a[i], b[j], acc[i][j]);
    }
  }
  #pragma unroll
  for (int i=0;i<TM;i++) {
    float* cp = C + (size_t)(m0+ty*TM+i)*ldc + n0 + tx*4;
    float4 r; r.x=acc[i][0]; r.y=acc[i][1]; r.z=acc[i][2]; r.w=acc[i][3];
    if constexpr (EPI==2) { const float* bp = bias + n0 + tx*4;
      r.x+=bp[0]; r.y+=bp[1]; r.z+=bp[2]; r.w+=bp[3]; }
    if constexpr (EPI==3) { const float* bp = bias + n0 + tx*4;
      r.x=softplusf_(r.x+bp[0]); r.y=softplusf_(r.y+bp[1]);
      r.z=softplusf_(r.z+bp[2]); r.w=softplusf_(r.w+bp[3]); }
    *(float4*)cp = r;
  }
}

// ---------------- split-bf16 MFMA GEMM: C[m,n] (+)= sum_k A[m,k]*W[n,k] ----------
// EPI: 0 = store, 1 = accumulate
template<int BM, int BN, int WR, int WC, int EPI>
__global__ __launch_bounds__(256) void gemm_mfma_k(
    const bf* __restrict__ Ahi, const bf* __restrict__ Alo,
    const bf* __restrict__ Whi, const bf* __restrict__ Wlo,
    float* __restrict__ C, int M, int N, int K)
{
  constexpr int BK = 32;
  constexpr int LDT = BK + 8;
  constexpr int WM = BM/WR, WN = BN/WC;
  constexpr int FM = WM/16, FN = WN/16;
  constexpr int CA = BM*4/256, CW = BN*4/256;
  __shared__ bf At[2][BM*LDT];
  __shared__ bf Wt[2][BN*LDT];
  const int t = threadIdx.x;
  const int w = t>>6, lane = t&63;
  const int wr = w%WR, wc = w/WR;
  const int lr = lane&15, lk = lane>>4;
  const int m0 = blockIdx.y*BM, n0 = blockIdx.x*BN;

  fx4 acc[FM][FN];
  #pragma unroll
  for (int i=0;i<FM;i++)
    #pragma unroll
    for (int j=0;j<FN;j++) acc[i][j] = fx4{0.f,0.f,0.f,0.f};

  for (int k0=0;k0<K;k0+=BK) {
    __syncthreads();
    #pragma unroll
    for (int q=0;q<CA;q++) {
      int c = q*256+t, row = c>>2, ko = (c&3)*8;
      size_t g = (size_t)(m0+row)*K + k0 + ko;
      float4 vh = *(const float4*)(Ahi+g);
      float4 vl = *(const float4*)(Alo+g);
      *(float4*)&At[0][row*LDT+ko] = vh;
      *(float4*)&At[1][row*LDT+ko] = vl;
    }
    #pragma unroll
    for (int q=0;q<CW;q++) {
      int c = q*256+t, row = c>>2, ko = (c&3)*8;
      size_t g = (size_t)(n0+row)*K + k0 + ko;
      float4 vh = *(const float4*)(Whi+g);
      float4 vl = *(const float4*)(Wlo+g);
      *(float4*)&Wt[0][row*LDT+ko] = vh;
      *(float4*)&Wt[1][row*LDT+ko] = vl;
    }
    __syncthreads();
    bx8 ah[FM], al[FM], bh[FN], bl[FN];
    #pragma unroll
    for (int i=0;i<FM;i++) {
      int row = wr*WM + i*16 + lr;
      ah[i] = *(const bx8*)&At[0][row*LDT + lk*8];
      al[i] = *(const bx8*)&At[1][row*LDT + lk*8];
    }
    #pragma unroll
    for (int j=0;j<FN;j++) {
      int row = wc*WN + j*16 + lr;
      bh[j] = *(const bx8*)&Wt[0][row*LDT + lk*8];
      bl[j] = *(const bx8*)&Wt[1][row*LDT + lk*8];
    }
    #pragma unroll
    for (int i=0;i<FM;i++)
      #pragma unroll
      for (int j=0;j<FN;j++) {
        acc[i][j] = __builtin_amdgcn_mfma_f32_16x16x32_bf16(ah[i], bh[j], acc[i][j], 0,0,0);
        acc[i][j] = __builtin_amdgcn_mfma_f32_16x16x32_bf16(ah[i], bl[j], acc[i][j], 0,0,0);
        acc[i][j] = __builtin_amdgcn_mfma_f32_16x16x32_bf16(al[i], bh[j], acc[i][j], 0,0,0);
      }
  }
  #pragma unroll
  for (int i=0;i<FM;i++)
    #pragma unroll
    for (int j=0;j<FN;j++) {
      int col = n0 + wc*WN + j*16 + lr;
      #pragma unroll
      for (int r=0;r<4;r++) {
        int row = m0 + wr*WM + i*16 + lk*4 + r;
        if constexpr (EPI==1) C[(size_t)row*N+col] += acc[i][j][r];
        else                  C[(size_t)row*N+col]  = acc[i][j][r];
      }
    }
}

// ---------------- fp32 -> bf16 hi/lo split ----------------
__global__ __launch_bounds__(256) void split_k(const float* __restrict__ in,
    bf* __restrict__ hi, bf* __restrict__ lo, int n4)
{
  int i = blockIdx.x*256 + threadIdx.x;
  if (i >= n4) return;
  float4 v = ((const float4*)in)[i];
  float f[4] = {v.x, v.y, v.z, v.w};
  bf hh[4], ll[4];
  #pragma unroll
  for (int j=0;j<4;j++) {
    hh[j] = __float2bfloat16(f[j]);
    ll[j] = __float2bfloat16(f[j] - __bfloat162float(hh[j]));
  }
  *(float2*)(hi + 4*(size_t)i) = *(float2*)hh;
  *(float2*)(lo + 4*(size_t)i) = *(float2*)ll;
}

// ---------------- rmsnorm over rows of 512, emits bf16 hi/lo ----------------
__global__ __launch_bounds__(256) void rmsnorm_k(const float* __restrict__ h,
    const float* __restrict__ nw, bf* __restrict__ hn_hi, bf* __restrict__ hn_lo)
{
  int m = blockIdx.x, t = threadIdx.x;
  const float* row = h + (size_t)m*DM;
  float v0 = row[t], v1 = row[t+256];
  float s = v0*v0 + v1*v1;
  #pragma unroll
  for (int off=32; off>=1; off>>=1) s += __shfl_xor(s, off, 64);
  __shared__ float red[4];
  if ((t&63)==0) red[t>>6] = s;
  __syncthreads();
  float tot = red[0]+red[1]+red[2]+red[3];
  float r = rsqrtf(tot*(1.0f/512.0f) + 1e-5f);
  float o0 = v0*r*nw[t], o1 = v1*r*nw[t+256];
  bf h0 = __float2bfloat16(o0), h1 = __float2bfloat16(o1);
  hn_hi[(size_t)m*DM+t]     = h0;
  hn_lo[(size_t)m*DM+t]     = __float2bfloat16(o0 - __bfloat162float(h0));
  hn_hi[(size_t)m*DM+t+256] = h1;
  hn_lo[(size_t)m*DM+t+256] = __float2bfloat16(o1 - __bfloat162float(h1));
}

// ---------------- causal depthwise conv (K=4) + silu; reads contiguous Xb ----------------
__global__ __launch_bounds__(256) void conv_silu_k(const float* __restrict__ Xb,
    const float* __restrict__ cw, const float* __restrict__ cb, float* __restrict__ xbc)
{
  int idx = blockIdx.x*256 + threadIdx.x;
  int e = idx & (EDIM-1);
  int m = idx >> 10;
  int l = m & (LSEQ-1);
  float4 w = *(const float4*)(cw + e*4);
  const float* xp = Xb + (size_t)m*EDIM + e;
  float acc = cb[e] + w.w * xp[0];
  if (l>0) acc += w.z * xp[-EDIM];
  if (l>1) acc += w.y * xp[-2*EDIM];
  if (l>2) acc += w.x * xp[-3*EDIM];
  xbc[idx] = siluf_(acc);
}

// ---------------- xproj: transpose W (64x1024 -> 1024x64) ----------------
__global__ __launch_bounds__(256) void wtrans_k(const float* __restrict__ W, float* __restrict__ Wt)
{
  __shared__ float tile[64][65];
  int kb = blockIdx.x;   // 16 k-tiles of 64
  for (int i=threadIdx.x; i<4096; i+=256) {
    int n = i>>6, c = i&63;
    tile[n][c] = W[(size_t)n*EDIM + kb*64 + c];
  }
  __syncthreads();
  for (int i=threadIdx.x; i<4096; i+=256) {
    int kk = i>>6, n = i&63;
    Wt[((size_t)kb*64+kk)*64 + n] = tile[n][kk];
  }
}

// ---------------- xproj split-K partials: Cp[kc][m][n], kc = K/256 chunk ----------------
__global__ __launch_bounds__(256) void xproj_part_k(const float* __restrict__ A,
    const float* __restrict__ Wt, float* __restrict__ Cp)
{
  constexpr int KC = 256;
  __shared__ float As[16][KC];          // 16 KB
  const int mb = blockIdx.x;            // 256 m-tiles of 16 rows
  const int kc = blockIdx.y;            // 4 k-chunks
  const int t  = threadIdx.x;
  const float* ap = A + ((size_t)mb*16)*EDIM + kc*KC;
  #pragma unroll
  for (int q=0;q<4;q++) {               // 1024 float4 loads / 256 threads
    int i = q*256 + t;
    int r = i>>6, c4 = i&63;
    float4 v = *(const float4*)(ap + (size_t)r*EDIM + c4*4);
    *(float4*)&As[r][c4*4] = v;
  }
  __syncthreads();
  const int m = t>>4, n0 = (t&15)*4;
  const float* wp = Wt + (size_t)kc*KC*64 + n0;
  float4 acc = {0.f,0.f,0.f,0.f};
  #pragma unroll 8
  for (int k=0;k<KC;k++) {
    float a = As[m][k];
    float4 w = *(const float4*)(wp + (size_t)k*64);
    acc.x = fmaf(a,w.x,acc.x); acc.y = fmaf(a,w.y,acc.y);
    acc.z = fmaf(a,w.z,acc.z); acc.w = fmaf(a,w.w,acc.w);
  }
  *(float4*)(Cp + ((size_t)kc*MTOK + (size_t)mb*16 + m)*64 + n0) = acc;
}

// ---------------- xproj reduce: C[m][n] = sum_kc Cp[kc][m][n] ----------------
__global__ __launch_bounds__(256) void xproj_red_k(const float* __restrict__ Cp,
    float* __restrict__ C)
{
  int i = blockIdx.x*256 + threadIdx.x;        // 65536 float4 slots
  const size_t stride = (size_t)MTOK*64/4;
  float4 a = ((const float4*)Cp)[i];
  float4 b = ((const float4*)Cp)[i + stride];
  float4 c = ((const float4*)Cp)[i + 2*stride];
  float4 d = ((const float4*)Cp)[i + 3*stride];
  float4 r; r.x=a.x+b.x+c.x+d.x; r.y=a.y+b.y+c.y+d.y;
  r.z=a.z+b.z+c.z+d.z; r.w=a.w+b.w+c.w+d.w;
  ((float4*)C)[i] = r;
}

// ---------------- chunked selective scan (NC=32, CH=32), full register preload ----------------
// P/S/Hinit layout: [b][c][n][ed]
__global__ __launch_bounds__(256,2) void scan_chunkA_k(const float* __restrict__ xbc,
    const float* __restrict__ dl, const float* __restrict__ dbc,
    const float* __restrict__ A_log,
    float* __restrict__ P, float* __restrict__ S)
{
  int ed = blockIdx.x*256 + threadIdx.x;
  int b = blockIdx.y, c = blockIdx.z;
  const int l0 = c*CH;
  __shared__ float Bs[CH][NST];
  for (int i=threadIdx.x; i<CH*NST; i+=256) {
    int row = i>>4, col = i&15;
    Bs[row][col] = dbc[((size_t)b*LSEQ + l0 + row)*64 + 32 + col];
  }
  __syncthreads();
  const float* dp = dl  + ((size_t)b*LSEQ + l0)*EDIM + ed;
  const float* xp = xbc + ((size_t)b*LSEQ + l0)*EDIM + ed;
  float dt[CH], xv[CH];
  #pragma unroll
  for (int l=0;l<CH;l++){ dt[l]=dp[(size_t)l*EDIM]; xv[l]=xp[(size_t)l*EDIM]; }
  float a[NST], hs[NST], pp[NST];
  #pragma unroll
  for (int n=0;n<NST;n++){ a[n] = -__expf(A_log[ed*NST+n]); hs[n]=0.f; pp[n]=1.f; }
  #pragma unroll
  for (int l=0;l<CH;l++) {
    float dx = dt[l]*xv[l];
    #pragma unroll
    for (int n=0;n<NST;n++) {
      float dA = __expf(dt[l]*a[n]);
      hs[n] = fmaf(dA, hs[n], dx*Bs[l][n]);
      pp[n] *= dA;
    }
  }
  size_t base = (((size_t)b*NC + c)*NST)*EDIM + ed;
  #pragma unroll
  for (int n=0;n<NST;n++) { P[base + (size_t)n*EDIM] = pp[n]; S[base + (size_t)n*EDIM] = hs[n]; }
}

__global__ __launch_bounds__(256) void scan_combine_k(float* __restrict__ PH, const float* __restrict__ S)
{
  int t = blockIdx.x*256 + threadIdx.x;       // n*EDIM+ed
  int b = blockIdx.y;
  const size_t stride = (size_t)NST*EDIM;
  size_t b0 = (size_t)b*NC*stride + t;
  float p[NC], s[NC];
  #pragma unroll
  for (int c=0;c<NC;c++){ p[c]=PH[b0+(size_t)c*stride]; s[c]=S[b0+(size_t)c*stride]; }
  float H = 0.f;
  #pragma unroll
  for (int c=0;c<NC;c++){ PH[b0+(size_t)c*stride] = H; H = fmaf(p[c], H, s[c]); }
}

// Pass C: replay from true init; fused y*silu(z); emits bf16 hi/lo.
__global__ __launch_bounds__(256,2) void scan_chunkC_k(const float* __restrict__ xbc,
    const float* __restrict__ dl, const float* __restrict__ dbc,
    const float* __restrict__ A_log, const float* __restrict__ Dp,
    const float* __restrict__ Hinit, const float* __restrict__ Z,
    bf* __restrict__ yz_hi, bf* __restrict__ yz_lo)
{
  int ed = blockIdx.x*256 + threadIdx.x;
  int b = blockIdx.y, c = blockIdx.z;
  const int l0 = c*CH;
  __shared__ float BCs[CH][32];
  for (int i=threadIdx.x; i<CH*32; i+=256) {
    int row = i>>5, col = i&31;
    BCs[row][col] = dbc[((size_t)b*LSEQ + l0 + row)*64 + 32 + col];
  }
  __syncthreads();
  const float* dp = dl  + ((size_t)b*LSEQ + l0)*EDIM + ed;
  const float* xp = xbc + ((size_t)b*LSEQ + l0)*EDIM + ed;
  const float* zp = Z   + ((size_t)b*LSEQ + l0)*EDIM + ed;
  float dt[CH], xv[CH], zv[CH];
  #pragma unroll
  for (int l=0;l<CH;l++){ dt[l]=dp[(size_t)l*EDIM]; xv[l]=xp[(size_t)l*EDIM]; zv[l]=zp[(size_t)l*EDIM]; }
  float a[NST], hs[NST];
  size_t base = (((size_t)b*NC + c)*NST)*EDIM + ed;
  #pragma unroll
  for (int n=0;n<NST;n++){ a[n] = -__expf(A_log[ed*NST+n]); hs[n] = Hinit[base + (size_t)n*EDIM]; }
  float Dv = Dp[ed];
  bf* yh = yz_hi + ((size_t)b*LSEQ + l0)*EDIM + ed;
  bf* yl = yz_lo + ((size_t)b*LSEQ + l0)*EDIM + ed;
  #pragma unroll
  for (int l=0;l<CH;l++) {
    float dx = dt[l]*xv[l];
    float yv = xv[l]*Dv;
    #pragma unroll
    for (int n=0;n<NST;n++) {
      float dA = __expf(dt[l]*a[n]);
      hs[n] = fmaf(dA, hs[n], dx*BCs[l][n]);
      yv = fmaf(hs[n], BCs[l][16+n], yv);
    }
    float g = yv * siluf_(zv[l]);
    bf gh = __float2bfloat16(g);
    yh[(size_t)l*EDIM] = gh;
    yl[(size_t)l*EDIM] = __float2bfloat16(g - __bfloat162float(gh));
  }
}

// ---------------- fc2 (D=512 -> 1) + sigmoid ----------------
__global__ __launch_bounds__(64) void fc2_k(const float* __restrict__ h,
    const float* __restrict__ w, const float* __restrict__ b, float* __restrict__ out)
{
  int m = blockIdx.x, t = threadIdx.x;
  float s = 0.f;
  #pragma unroll
  for (int j=0;j<8;j++) { int k = t + j*64; s = fmaf(h[(size_t)m*DM+k], w[k], s); }
  #pragma unroll
  for (int off=32; off>=1; off>>=1) s += __shfl_xor(s, off, 64);
  if (t==0) out[m] = sigmoidf_(s + b[0]);
}

extern "C" void kernel_launch(void* const* d_in, const int* in_sizes, int n_in,
                              void* d_out, int out_size, void* d_ws, size_t ws_size,
                              hipStream_t stream) {
  const float* x         = (const float*)d_in[0];
  const float* fc1_w     = (const float*)d_in[1];
  const float* fc1_b     = (const float*)d_in[2];
  const float* fc2_w     = (const float*)d_in[3];
  const float* fc2_b     = (const float*)d_in[4];
  const float* norm_w    = (const float*)d_in[5];
  const float* in_proj_w = (const float*)d_in[6];
  const float* conv_w    = (const float*)d_in[7];
  const float* conv_b    = (const float*)d_in[8];
  const float* xproj_w   = (const float*)d_in[9];
  const float* dtproj_w  = (const float*)d_in[10];
  const float* dtproj_b  = (const float*)d_in[11];
  const float* A_log     = (const float*)d_in[12];
  const float* D_param   = (const float*)d_in[13];
  const float* out_proj_w= (const float*)d_in[14];
  float* out = (float*)d_out;

  char* w8 = (char*)d_ws;                  // total footprint: 103 MB
  float* h    = (float*)(w8 +  0*MB);      //  8 MB
  float* Xb   = (float*)(w8 +  8*MB);      // 16 MB (dead after conv)
  float* PH   = (float*)(w8 +  8*MB);      //  8 MB (alias Xb; live scanA..scanC)
  float* Z    = (float*)(w8 + 24*MB);      // 16 MB (live till scanC)
  float* xbc  = (float*)(w8 + 40*MB);      // 16 MB
  float* dl   = (float*)(w8 + 56*MB);      // 16 MB
  float* dbcw = (float*)(w8 + 72*MB);      //  1 MB
  bf*    win_hi = (bf*)(w8 + 73*MB);       //  2 MB (dead after in_proj)
  float* Wt     = (float*)(w8 + 73*MB);    //  256 KB (alias win; live wtrans..xproj)
  bf*    win_lo = (bf*)(w8 + 75*MB);       //  2 MB
  bf*    wout_hi= (bf*)(w8 + 77*MB);       //  1 MB
  bf*    wout_lo= (bf*)(w8 + 78*MB);       //  1 MB
  bf*    hn_hi  = (bf*)(w8 + 79*MB);       //  4 MB (dead after in_proj)
  bf*    hn_lo  = (bf*)(w8 + 83*MB);       //  4 MB
  float* Send   = (float*)(w8 + 79*MB);    //  8 MB (alias hn; live scanA..combine)
  float* Cp     = (float*)(w8 + 79*MB);    //  4 MB (alias hn; live xproj_part..red, before Send)
  bf*    yz_hi  = (bf*)(w8 + 87*MB);       //  8 MB
  bf*    yz_lo  = (bf*)(w8 + 95*MB);       //  8 MB

  // fc1: h = x @ fc1_w^T + fc1_b    (4096 x 512, K=32)
  gemm_k<128,64,2><<<dim3(DM/64, MTOK/128), 256, 0, stream>>>(
      x, fc1_w, fc1_b, h, MTOK, DM, DIN, DIN, DIN, DM);

  for (int i=0;i<4;i++) {
    rmsnorm_k<<<MTOK, 256, 0, stream>>>(h, norm_w + (size_t)i*DM, hn_hi, hn_lo);
    split_k<<<(2048*512/4)/256, 256, 0, stream>>>(
        in_proj_w + (size_t)i*2048*DM, win_hi, win_lo, 2048*512/4);
    // in_proj as two N=1024 MFMA GEMMs -> Xb, Z
    gemm_mfma_k<128,128,2,2,0><<<dim3(EDIM/128, MTOK/128), 256, 0, stream>>>(
        hn_hi, hn_lo, win_hi, win_lo, Xb, MTOK, EDIM, DM);
    gemm_mfma_k<128,128,2,2,0><<<dim3(EDIM/128, MTOK/128), 256, 0, stream>>>(
        hn_hi, hn_lo, win_hi + (size_t)EDIM*DM, win_lo + (size_t)EDIM*DM, Z, MTOK, EDIM, DM);
    conv_silu_k<<<(MTOK*EDIM)/256, 256, 0, stream>>>(
        Xb, conv_w + (size_t)i*EDIM*4, conv_b + (size_t)i*EDIM, xbc);
    // xproj: transpose weight, split-K partials (1024 blocks), reduce
    wtrans_k<<<16, 256, 0, stream>>>(xproj_w + (size_t)i*64*EDIM, Wt);
    xproj_part_k<<<dim3(MTOK/16, 4), 256, 0, stream>>>(xbc, Wt, Cp);
    xproj_red_k<<<(MTOK*64/4)/256, 256, 0, stream>>>(Cp, dbcw);
    // delta = softplus(dt @ dtproj_w^T + dtproj_b)   (4096 x 1024, K=32, lda=64)
    gemm_k<128,64,3><<<dim3(EDIM/64, MTOK/128), 256, 0, stream>>>(
        dbcw, dtproj_w + (size_t)i*EDIM*RANK, dtproj_b + (size_t)i*EDIM, dl,
        MTOK, EDIM, RANK, 64, RANK, EDIM);
    // chunked selective scan
    scan_chunkA_k<<<dim3(EDIM/256, BB, NC), 256, 0, stream>>>(
        xbc, dl, dbcw, A_log + (size_t)i*EDIM*NST, PH, Send);
    scan_combine_k<<<dim3(NST*EDIM/256, BB), 256, 0, stream>>>(PH, Send);
    scan_chunkC_k<<<dim3(EDIM/256, BB, NC), 256, 0, stream>>>(
        xbc, dl, dbcw, A_log + (size_t)i*EDIM*NST, D_param + (size_t)i*EDIM, PH,
        Z, yz_hi, yz_lo);
    split_k<<<(512*1024/4)/256, 256, 0, stream>>>(
        out_proj_w + (size_t)i*DM*EDIM, wout_hi, wout_lo, 512*1024/4);
    // h += yz @ out_proj_w^T  (4096 x 512, K=1024)  [MFMA, accumulate]
    gemm_mfma_k<128,64,4,1,1><<<dim3(DM/64, MTOK/128), 256, 0, stream>>>(
        yz_hi, yz_lo, wout_hi, wout_lo, h, MTOK, DM, EDIM);
  }

  // out = sigmoid(h @ fc2_w^T + fc2_b)
  fc2_k<<<MTOK, 64, 0, stream>>>(h, fc2_w, fc2_b, out);
}

// Round 7
// 884.255 us; speedup vs baseline: 5.5485x; 1.1719x over previous
//
#include <hip/hip_runtime.h>
#include <hip/hip_bf16.h>
#include <cmath>

#define BB 4
#define LSEQ 1024
#define DIN 32
#define DM 512
#define EDIM 1024
#define NST 16
#define RANK 32
#define MTOK (BB*LSEQ)   // 4096
#define NC 32            // scan chunks
#define CH (LSEQ/NC)     // 32 steps per chunk
#define MB 1048576ull

typedef __attribute__((ext_vector_type(8))) short bx8;
typedef __attribute__((ext_vector_type(4))) float fx4;
typedef __hip_bfloat16 bf;

__device__ __forceinline__ float sigmoidf_(float x){ return 1.f/(1.f+__expf(-x)); }
__device__ __forceinline__ float softplusf_(float x){ return fmaxf(x,0.f) + log1pf(__expf(-fabsf(x))); }
__device__ __forceinline__ float siluf_(float x){ return x * sigmoidf_(x); }

// async global->LDS, 16B per lane; LDS dest = wave-uniform base + lane*16
__device__ __forceinline__ void gl16(const bf* g, bf* l) {
  __builtin_amdgcn_global_load_lds(
      (const __attribute__((address_space(1))) void*)g,
      (__attribute__((address_space(3))) void*)l, 16, 0, 0);
}

// ---------------- fp32 tiled GEMM (fc1, dtproj):  C[m,n] = sum_k A[m,k]*W[n,k] ----------------
// EPI: 0 = store, 2 = +bias, 3 = softplus(x+bias)
template<int BM, int BN, int EPI>
__global__ __launch_bounds__(256) void gemm_k(const float* __restrict__ A,
    const float* __restrict__ W, const float* __restrict__ bias,
    float* __restrict__ C, int M, int N, int K, int lda, int ldw, int ldc)
{
  constexpr int BK = 16;
  constexpr int TX = BN/4;
  constexpr int TY = 256/TX;
  constexpr int TM = BM/TY;
  __shared__ float As[BK][BM];
  __shared__ float Ws[BK][BN];
  const int t = threadIdx.x;
  const int n0 = blockIdx.x*BN, m0 = blockIdx.y*BM;
  const int tx = t % TX, ty = t / TX;
  float acc[TM][4];
  #pragma unroll
  for (int i=0;i<TM;i++){ acc[i][0]=0.f;acc[i][1]=0.f;acc[i][2]=0.f;acc[i][3]=0.f; }

  for (int k0=0;k0<K;k0+=BK) {
    __syncthreads();
    for (int f=t; f<BM*4; f+=256) {
      int row=f>>2, kq=f&3;
      float4 v = *(const float4*)(A + (size_t)(m0+row)*lda + (k0+kq*4));
      As[kq*4+0][row]=v.x; As[kq*4+1][row]=v.y; As[kq*4+2][row]=v.z; As[kq*4+3][row]=v.w;
    }
    for (int f=t; f<BN*4; f+=256) {
      int row=f>>2, kq=f&3;
      float4 v = *(const float4*)(W + (size_t)(n0+row)*ldw + (k0+kq*4));
      Ws[kq*4+0][row]=v.x; Ws[kq*4+1][row]=v.y; Ws[kq*4+2][row]=v.z; Ws[kq*4+3][row]=v.w;
    }
    __syncthreads();
    #pragma unroll
    for (int kk=0;kk<BK;kk++) {
      float a[TM], b[4];
      #pragma unroll
      for (int j=0;j<4;j++) b[j] = Ws[kk][tx*4+j];
      #pragma unroll
      for (int i=0;i<TM;i++) a[i] = As[kk][ty*TM+i];
      #pragma unroll
      for (int i=0;i<TM;i++)
        #pragma unroll
        for (int j=0;j<4;j++) acc[i][j] = fmaf(a[i], b[j], acc[i][j]);
    }
  }
  #pragma unroll
  for (int i=0;i<TM;i++) {
    float* cp = C + (size_t)(m0+ty*TM+i)*ldc + n0 + tx*4;
    float4 r; r.x=acc[i][0]; r.y=acc[i][1]; r.z=acc[i][2]; r.w=acc[i][3];
    if constexpr (EPI==2) { const float* bp = bias + n0 + tx*4;
      r.x+=bp[0]; r.y+=bp[1]; r.z+=bp[2]; r.w+=bp[3]; }
    if constexpr (EPI==3) { const float* bp = bias + n0 + tx*4;
      r.x=softplusf_(r.x+bp[0]); r.y=softplusf_(r.y+bp[1]);
      r.z=softplusf_(r.z+bp[2]); r.w=softplusf_(r.w+bp[3]); }
    *(float4*)cp = r;
  }
}

// ------- split-bf16 MFMA GEMM v2 (global_load_lds, linear LDS, XCD swizzle) -------
// C[m,n] (+)= sum_k A[m,k]*W[n,k];  cols < nsplit -> Cx, cols >= nsplit -> Cz (col-nsplit)
// EPI: 0 = store, 1 = accumulate. Requires grid blocks % 8 == 0, K % 32 == 0.
template<int BM, int BN, int WR, int WC, int EPI>
__global__ __launch_bounds__(256) void gemm_mfma2_k(
    const bf* __restrict__ Ahi, const bf* __restrict__ Alo,
    const bf* __restrict__ Whi, const bf* __restrict__ Wlo,
    float* __restrict__ Cx, float* __restrict__ Cz, int nsplit,
    int M, int N, int K, int ldc)
{
  constexpr int WM = BM/WR, WN = BN/WC;
  constexpr int FM = WM/16, FN = WN/16;
  __shared__ bf sAh[BM*32], sAl[BM*32], sWh[BN*32], sWl[BN*32];
  const int t = threadIdx.x;
  const int w = t>>6, lane = t&63;
  const int wr = w%WR, wc = w/WR;
  const int lr = lane&15, lk = lane>>4;
  const int rowl = lane>>2, coll = (lane&3)*8;

  // bijective XCD swizzle: each XCD gets a contiguous chunk of logical tiles
  const int gx = gridDim.x;
  const int flat = blockIdx.y*gx + blockIdx.x;
  const int cpx = (gx*gridDim.y)>>3;
  const int logical = (flat&7)*cpx + (flat>>3);
  const int m0 = (logical/gx)*BM, n0 = (logical%gx)*BN;

  fx4 acc[FM][FN];
  #pragma unroll
  for (int i=0;i<FM;i++)
    #pragma unroll
    for (int j=0;j<FN;j++) acc[i][j] = fx4{0.f,0.f,0.f,0.f};

  for (int k0=0;k0<K;k0+=32) {
    __syncthreads();                          // prior reads done before overwrite
    {
      const int rb = w*(BM/4);
      #pragma unroll
      for (int q=0;q<BM/64;q++) {
        int r = rb + q*16 + rowl;
        size_t g = (size_t)(m0+r)*K + k0 + coll;
        gl16(Ahi+g, &sAh[(rb+q*16)*32]);
        gl16(Alo+g, &sAl[(rb+q*16)*32]);
      }
    }
    {
      const int rb = w*(BN/4);
      #pragma unroll
      for (int q=0;q<BN/64;q++) {
        int r = rb + q*16 + rowl;
        size_t g = (size_t)(n0+r)*K + k0 + coll;
        gl16(Whi+g, &sWh[(rb+q*16)*32]);
        gl16(Wlo+g, &sWl[(rb+q*16)*32]);
      }
    }
    __syncthreads();                          // drains vmcnt -> LDS data ready
    bx8 ah[FM], al[FM], bh[FN], bl[FN];
    #pragma unroll
    for (int i=0;i<FM;i++) {
      int row = wr*WM + i*16 + lr;
      ah[i] = *(const bx8*)&sAh[row*32 + lk*8];
      al[i] = *(const bx8*)&sAl[row*32 + lk*8];
    }
    #pragma unroll
    for (int j=0;j<FN;j++) {
      int row = wc*WN + j*16 + lr;
      bh[j] = *(const bx8*)&sWh[row*32 + lk*8];
      bl[j] = *(const bx8*)&sWl[row*32 + lk*8];
    }
    #pragma unroll
    for (int i=0;i<FM;i++)
      #pragma unroll
      for (int j=0;j<FN;j++) {
        acc[i][j] = __builtin_amdgcn_mfma_f32_16x16x32_bf16(ah[i], bh[j], acc[i][j], 0,0,0);
        acc[i][j] = __builtin_amdgcn_mfma_f32_16x16x32_bf16(ah[i], bl[j], acc[i][j], 0,0,0);
        acc[i][j] = __builtin_amdgcn_mfma_f32_16x16x32_bf16(al[i], bh[j], acc[i][j], 0,0,0);
      }
  }
  #pragma unroll
  for (int j=0;j<FN;j++) {
    int coln = n0 + wc*WN + j*16 + lr;
    float* Cb; int cc;
    if (coln < nsplit) { Cb = Cx; cc = coln; } else { Cb = Cz; cc = coln - nsplit; }
    #pragma unroll
    for (int i=0;i<FM;i++) {
      #pragma unroll
      for (int r=0;r<4;r++) {
        int row = m0 + wr*WM + i*16 + lk*4 + r;
        if constexpr (EPI==1) Cb[(size_t)row*ldc+cc] += acc[i][j][r];
        else                  Cb[(size_t)row*ldc+cc]  = acc[i][j][r];
      }
    }
  }
}

// ---------------- fp32 -> bf16 hi/lo split ----------------
__global__ __launch_bounds__(256) void split_k(const float* __restrict__ in,
    bf* __restrict__ hi, bf* __restrict__ lo, int n4)
{
  int i = blockIdx.x*256 + threadIdx.x;
  if (i >= n4) return;
  float4 v = ((const float4*)in)[i];
  float f[4] = {v.x, v.y, v.z, v.w};
  bf hh[4], ll[4];
  #pragma unroll
  for (int j=0;j<4;j++) {
    hh[j] = __float2bfloat16(f[j]);
    ll[j] = __float2bfloat16(f[j] - __bfloat162float(hh[j]));
  }
  *(float2*)(hi + 4*(size_t)i) = *(float2*)hh;
  *(float2*)(lo + 4*(size_t)i) = *(float2*)ll;
}

// ---------------- rmsnorm over rows of 512, emits bf16 hi/lo ----------------
__global__ __launch_bounds__(256) void rmsnorm_k(const float* __restrict__ h,
    const float* __restrict__ nw, bf* __restrict__ hn_hi, bf* __restrict__ hn_lo)
{
  int m = blockIdx.x, t = threadIdx.x;
  const float* row = h + (size_t)m*DM;
  float v0 = row[t], v1 = row[t+256];
  float s = v0*v0 + v1*v1;
  #pragma unroll
  for (int off=32; off>=1; off>>=1) s += __shfl_xor(s, off, 64);
  __shared__ float red[4];
  if ((t&63)==0) red[t>>6] = s;
  __syncthreads();
  float tot = red[0]+red[1]+red[2]+red[3];
  float r = rsqrtf(tot*(1.0f/512.0f) + 1e-5f);
  float o0 = v0*r*nw[t], o1 = v1*r*nw[t+256];
  bf h0 = __float2bfloat16(o0), h1 = __float2bfloat16(o1);
  hn_hi[(size_t)m*DM+t]     = h0;
  hn_lo[(size_t)m*DM+t]     = __float2bfloat16(o0 - __bfloat162float(h0));
  hn_hi[(size_t)m*DM+t+256] = h1;
  hn_lo[(size_t)m*DM+t+256] = __float2bfloat16(o1 - __bfloat162float(h1));
}

// ---------------- causal depthwise conv (K=4) + silu; reads contiguous Xb ----------------
__global__ __launch_bounds__(256) void conv_silu_k(const float* __restrict__ Xb,
    const float* __restrict__ cw, const float* __restrict__ cb, float* __restrict__ xbc)
{
  int idx = blockIdx.x*256 + threadIdx.x;
  int e = idx & (EDIM-1);
  int m = idx >> 10;
  int l = m & (LSEQ-1);
  float4 w = *(const float4*)(cw + e*4);
  const float* xp = Xb + (size_t)m*EDIM + e;
  float acc = cb[e] + w.w * xp[0];
  if (l>0) acc += w.z * xp[-EDIM];
  if (l>1) acc += w.y * xp[-2*EDIM];
  if (l>2) acc += w.x * xp[-3*EDIM];
  xbc[idx] = siluf_(acc);
}

// ---------------- xproj: transpose W (64x1024 -> 1024x64) ----------------
__global__ __launch_bounds__(256) void wtrans_k(const float* __restrict__ W, float* __restrict__ Wt)
{
  __shared__ float tile[64][65];
  int kb = blockIdx.x;   // 16 k-tiles of 64
  for (int i=threadIdx.x; i<4096; i+=256) {
    int n = i>>6, c = i&63;
    tile[n][c] = W[(size_t)n*EDIM + kb*64 + c];
  }
  __syncthreads();
  for (int i=threadIdx.x; i<4096; i+=256) {
    int kk = i>>6, n = i&63;
    Wt[((size_t)kb*64+kk)*64 + n] = tile[n][kk];
  }
}

// ---------------- xproj split-K partials: Cp[kc][m][n], kc = K/256 chunk ----------------
__global__ __launch_bounds__(256) void xproj_part_k(const float* __restrict__ A,
    const float* __restrict__ Wt, float* __restrict__ Cp)
{
  constexpr int KC = 256;
  __shared__ float As[16][KC];          // 16 KB
  const int mb = blockIdx.x;            // 256 m-tiles of 16 rows
  const int kc = blockIdx.y;            // 4 k-chunks
  const int t  = threadIdx.x;
  const float* ap = A + ((size_t)mb*16)*EDIM + kc*KC;
  #pragma unroll
  for (int q=0;q<4;q++) {               // 1024 float4 loads / 256 threads
    int i = q*256 + t;
    int r = i>>6, c4 = i&63;
    float4 v = *(const float4*)(ap + (size_t)r*EDIM + c4*4);
    *(float4*)&As[r][c4*4] = v;
  }
  __syncthreads();
  const int m = t>>4, n0 = (t&15)*4;
  const float* wp = Wt + (size_t)kc*KC*64 + n0;
  float4 acc = {0.f,0.f,0.f,0.f};
  #pragma unroll 8
  for (int k=0;k<KC;k++) {
    float a = As[m][k];
    float4 w = *(const float4*)(wp + (size_t)k*64);
    acc.x = fmaf(a,w.x,acc.x); acc.y = fmaf(a,w.y,acc.y);
    acc.z = fmaf(a,w.z,acc.z); acc.w = fmaf(a,w.w,acc.w);
  }
  *(float4*)(Cp + ((size_t)kc*MTOK + (size_t)mb*16 + m)*64 + n0) = acc;
}

// ---------------- xproj reduce: C[m][n] = sum_kc Cp[kc][m][n] ----------------
__global__ __launch_bounds__(256) void xproj_red_k(const float* __restrict__ Cp,
    float* __restrict__ C)
{
  int i = blockIdx.x*256 + threadIdx.x;        // 65536 float4 slots
  const size_t stride = (size_t)MTOK*64/4;
  float4 a = ((const float4*)Cp)[i];
  float4 b = ((const float4*)Cp)[i + stride];
  float4 c = ((const float4*)Cp)[i + 2*stride];
  float4 d = ((const float4*)Cp)[i + 3*stride];
  float4 r; r.x=a.x+b.x+c.x+d.x; r.y=a.y+b.y+c.y+d.y;
  r.z=a.z+b.z+c.z+d.z; r.w=a.w+b.w+c.w+d.w;
  ((float4*)C)[i] = r;
}

// ---------------- chunked selective scan (NC=32, CH=32), full register preload ----------------
// P/S/Hinit layout: [b][c][n][ed]
__global__ __launch_bounds__(256,2) void scan_chunkA_k(const float* __restrict__ xbc,
    const float* __restrict__ dl, const float* __restrict__ dbc,
    const float* __restrict__ A_log,
    float* __restrict__ P, float* __restrict__ S)
{
  int ed = blockIdx.x*256 + threadIdx.x;
  int b = blockIdx.y, c = blockIdx.z;
  const int l0 = c*CH;
  __shared__ float Bs[CH][NST];
  for (int i=threadIdx.x; i<CH*NST; i+=256) {
    int row = i>>4, col = i&15;
    Bs[row][col] = dbc[((size_t)b*LSEQ + l0 + row)*64 + 32 + col];
  }
  __syncthreads();
  const float* dp = dl  + ((size_t)b*LSEQ + l0)*EDIM + ed;
  const float* xp = xbc + ((size_t)b*LSEQ + l0)*EDIM + ed;
  float dt[CH], xv[CH];
  #pragma unroll
  for (int l=0;l<CH;l++){ dt[l]=dp[(size_t)l*EDIM]; xv[l]=xp[(size_t)l*EDIM]; }
  float a[NST], hs[NST], pp[NST];
  #pragma unroll
  for (int n=0;n<NST;n++){ a[n] = -__expf(A_log[ed*NST+n]); hs[n]=0.f; pp[n]=1.f; }
  #pragma unroll
  for (int l=0;l<CH;l++) {
    float dx = dt[l]*xv[l];
    #pragma unroll
    for (int n=0;n<NST;n++) {
      float dA = __expf(dt[l]*a[n]);
      hs[n] = fmaf(dA, hs[n], dx*Bs[l][n]);
      pp[n] *= dA;
    }
  }
  size_t base = (((size_t)b*NC + c)*NST)*EDIM + ed;
  #pragma unroll
  for (int n=0;n<NST;n++) { P[base + (size_t)n*EDIM] = pp[n]; S[base + (size_t)n*EDIM] = hs[n]; }
}

__global__ __launch_bounds__(256) void scan_combine_k(float* __restrict__ PH, const float* __restrict__ S)
{
  int t = blockIdx.x*256 + threadIdx.x;       // n*EDIM+ed
  int b = blockIdx.y;
  const size_t stride = (size_t)NST*EDIM;
  size_t b0 = (size_t)b*NC*stride + t;
  float p[NC], s[NC];
  #pragma unroll
  for (int c=0;c<NC;c++){ p[c]=PH[b0+(size_t)c*stride]; s[c]=S[b0+(size_t)c*stride]; }
  float H = 0.f;
  #pragma unroll
  for (int c=0;c<NC;c++){ PH[b0+(size_t)c*stride] = H; H = fmaf(p[c], H, s[c]); }
}

// Pass C: replay from true init; fused y*silu(z); emits bf16 hi/lo.
__global__ __launch_bounds__(256,2) void scan_chunkC_k(const float* __restrict__ xbc,
    const float* __restrict__ dl, const float* __restrict__ dbc,
    const float* __restrict__ A_log, const float* __restrict__ Dp,
    const float* __restrict__ Hinit, const float* __restrict__ Z,
    bf* __restrict__ yz_hi, bf* __restrict__ yz_lo)
{
  int ed = blockIdx.x*256 + threadIdx.x;
  int b = blockIdx.y, c = blockIdx.z;
  const int l0 = c*CH;
  __shared__ float BCs[CH][32];
  for (int i=threadIdx.x; i<CH*32; i+=256) {
    int row = i>>5, col = i&31;
    BCs[row][col] = dbc[((size_t)b*LSEQ + l0 + row)*64 + 32 + col];
  }
  __syncthreads();
  const float* dp = dl  + ((size_t)b*LSEQ + l0)*EDIM + ed;
  const float* xp = xbc + ((size_t)b*LSEQ + l0)*EDIM + ed;
  const float* zp = Z   + ((size_t)b*LSEQ + l0)*EDIM + ed;
  float dt[CH], xv[CH], zv[CH];
  #pragma unroll
  for (int l=0;l<CH;l++){ dt[l]=dp[(size_t)l*EDIM]; xv[l]=xp[(size_t)l*EDIM]; zv[l]=zp[(size_t)l*EDIM]; }
  float a[NST], hs[NST];
  size_t base = (((size_t)b*NC + c)*NST)*EDIM + ed;
  #pragma unroll
  for (int n=0;n<NST;n++){ a[n] = -__expf(A_log[ed*NST+n]); hs[n] = Hinit[base + (size_t)n*EDIM]; }
  float Dv = Dp[ed];
  bf* yh = yz_hi + ((size_t)b*LSEQ + l0)*EDIM + ed;
  bf* yl = yz_lo + ((size_t)b*LSEQ + l0)*EDIM + ed;
  #pragma unroll
  for (int l=0;l<CH;l++) {
    float dx = dt[l]*xv[l];
    float yv = xv[l]*Dv;
    #pragma unroll
    for (int n=0;n<NST;n++) {
      float dA = __expf(dt[l]*a[n]);
      hs[n] = fmaf(dA, hs[n], dx*BCs[l][n]);
      yv = fmaf(hs[n], BCs[l][16+n], yv);
    }
    float g = yv * siluf_(zv[l]);
    bf gh = __float2bfloat16(g);
    yh[(size_t)l*EDIM] = gh;
    yl[(size_t)l*EDIM] = __float2bfloat16(g - __bfloat162float(gh));
  }
}

// ---------------- fc2 (D=512 -> 1) + sigmoid ----------------
__global__ __launch_bounds__(64) void fc2_k(const float* __restrict__ h,
    const float* __restrict__ w, const float* __restrict__ b, float* __restrict__ out)
{
  int m = blockIdx.x, t = threadIdx.x;
  float s = 0.f;
  #pragma unroll
  for (int j=0;j<8;j++) { int k = t + j*64; s = fmaf(h[(size_t)m*DM+k], w[k], s); }
  #pragma unroll
  for (int off=32; off>=1; off>>=1) s += __shfl_xor(s, off, 64);
  if (t==0) out[m] = sigmoidf_(s + b[0]);
}

extern "C" void kernel_launch(void* const* d_in, const int* in_sizes, int n_in,
                              void* d_out, int out_size, void* d_ws, size_t ws_size,
                              hipStream_t stream) {
  const float* x         = (const float*)d_in[0];
  const float* fc1_w     = (const float*)d_in[1];
  const float* fc1_b     = (const float*)d_in[2];
  const float* fc2_w     = (const float*)d_in[3];
  const float* fc2_b     = (const float*)d_in[4];
  const float* norm_w    = (const float*)d_in[5];
  const float* in_proj_w = (const float*)d_in[6];
  const float* conv_w    = (const float*)d_in[7];
  const float* conv_b    = (const float*)d_in[8];
  const float* xproj_w   = (const float*)d_in[9];
  const float* dtproj_w  = (const float*)d_in[10];
  const float* dtproj_b  = (const float*)d_in[11];
  const float* A_log     = (const float*)d_in[12];
  const float* D_param   = (const float*)d_in[13];
  const float* out_proj_w= (const float*)d_in[14];
  float* out = (float*)d_out;

  char* w8 = (char*)d_ws;                  // total footprint: 103 MB
  float* h    = (float*)(w8 +  0*MB);      //  8 MB
  float* Xb   = (float*)(w8 +  8*MB);      // 16 MB (dead after conv)
  float* PH   = (float*)(w8 +  8*MB);      //  8 MB (alias Xb; live scanA..scanC)
  float* Z    = (float*)(w8 + 24*MB);      // 16 MB (live till scanC)
  float* xbc  = (float*)(w8 + 40*MB);      // 16 MB
  float* dl   = (float*)(w8 + 56*MB);      // 16 MB
  float* dbcw = (float*)(w8 + 72*MB);      //  1 MB
  bf*    win_hi = (bf*)(w8 + 73*MB);       //  2 MB (dead after in_proj)
  float* Wt     = (float*)(w8 + 73*MB);    //  256 KB (alias win; live wtrans..xproj)
  bf*    win_lo = (bf*)(w8 + 75*MB);       //  2 MB
  bf*    wout_hi= (bf*)(w8 + 77*MB);       //  1 MB
  bf*    wout_lo= (bf*)(w8 + 78*MB);       //  1 MB
  bf*    hn_hi  = (bf*)(w8 + 79*MB);       //  4 MB (dead after in_proj)
  bf*    hn_lo  = (bf*)(w8 + 83*MB);       //  4 MB
  float* Send   = (float*)(w8 + 79*MB);    //  8 MB (alias hn; live scanA..combine)
  float* Cp     = (float*)(w8 + 79*MB);    //  4 MB (alias hn; live xproj_part..red, before Send)
  bf*    yz_hi  = (bf*)(w8 + 87*MB);       //  8 MB
  bf*    yz_lo  = (bf*)(w8 + 95*MB);       //  8 MB

  // fc1: h = x @ fc1_w^T + fc1_b    (4096 x 512, K=32)
  gemm_k<128,64,2><<<dim3(DM/64, MTOK/128), 256, 0, stream>>>(
      x, fc1_w, fc1_b, h, MTOK, DM, DIN, DIN, DIN, DM);

  for (int i=0;i<4;i++) {
    rmsnorm_k<<<MTOK, 256, 0, stream>>>(h, norm_w + (size_t)i*DM, hn_hi, hn_lo);
    split_k<<<(2048*512/4)/256, 256, 0, stream>>>(
        in_proj_w + (size_t)i*2048*DM, win_hi, win_lo, 2048*512/4);
    // in_proj merged: N=2048, cols<1024 -> Xb, cols>=1024 -> Z  (512 blocks, 2/CU)
    gemm_mfma2_k<128,128,2,2,0><<<dim3(2048/128, MTOK/128), 256, 0, stream>>>(
        hn_hi, hn_lo, win_hi, win_lo, Xb, Z, 1024, MTOK, 2048, DM, EDIM);
    conv_silu_k<<<(MTOK*EDIM)/256, 256, 0, stream>>>(
        Xb, conv_w + (size_t)i*EDIM*4, conv_b + (size_t)i*EDIM, xbc);
    // xproj: transpose weight, split-K partials (1024 blocks), reduce
    wtrans_k<<<16, 256, 0, stream>>>(xproj_w + (size_t)i*64*EDIM, Wt);
    xproj_part_k<<<dim3(MTOK/16, 4), 256, 0, stream>>>(xbc, Wt, Cp);
    xproj_red_k<<<(MTOK*64/4)/256, 256, 0, stream>>>(Cp, dbcw);
    // delta = softplus(dt @ dtproj_w^T + dtproj_b)   (4096 x 1024, K=32, lda=64)
    gemm_k<128,64,3><<<dim3(EDIM/64, MTOK/128), 256, 0, stream>>>(
        dbcw, dtproj_w + (size_t)i*EDIM*RANK, dtproj_b + (size_t)i*EDIM, dl,
        MTOK, EDIM, RANK, 64, RANK, EDIM);
    // chunked selective scan
    scan_chunkA_k<<<dim3(EDIM/256, BB, NC), 256, 0, stream>>>(
        xbc, dl, dbcw, A_log + (size_t)i*EDIM*NST, PH, Send);
    scan_combine_k<<<dim3(NST*EDIM/256, BB), 256, 0, stream>>>(PH, Send);
    scan_chunkC_k<<<dim3(EDIM/256, BB, NC), 256, 0, stream>>>(
        xbc, dl, dbcw, A_log + (size_t)i*EDIM*NST, D_param + (size_t)i*EDIM, PH,
        Z, yz_hi, yz_lo);
    split_k<<<(512*1024/4)/256, 256, 0, stream>>>(
        out_proj_w + (size_t)i*DM*EDIM, wout_hi, wout_lo, 512*1024/4);
    // h += yz @ out_proj_w^T  (4096 x 512, K=1024)  [64x64 tiles, 512 blocks, 2/CU]
    gemm_mfma2_k<64,64,2,2,1><<<dim3(DM/64, MTOK/64), 256, 0, stream>>>(
        yz_hi, yz_lo, wout_hi, wout_lo, h, h, DM, MTOK, DM, EDIM, DM);
  }

  // out = sigmoid(h @ fc2_w^T + fc2_b)
  fc2_k<<<MTOK, 64, 0, stream>>>(h, fc2_w, fc2_b, out);
}

// Round 13
// 863.208 us; speedup vs baseline: 5.6838x; 1.0244x over previous
//
#include <hip/hip_runtime.h>
#include <hip/hip_bf16.h>
#include <cmath>

#define BB 4
#define LSEQ 1024
#define DIN 32
#define DM 512
#define EDIM 1024
#define NST 16
#define RANK 32
#define MTOK (BB*LSEQ)   // 4096
#define NC 32            // scan chunks
#define CH (LSEQ/NC)     // 32 steps per chunk
#define MB 1048576ull

typedef __attribute__((ext_vector_type(8))) short bx8;
typedef __attribute__((ext_vector_type(4))) float fx4;
typedef __hip_bfloat16 bf;

__device__ __forceinline__ float sigmoidf_(float x){ return 1.f/(1.f+__expf(-x)); }
__device__ __forceinline__ float softplusf_(float x){ return fmaxf(x,0.f) + log1pf(__expf(-fabsf(x))); }
__device__ __forceinline__ float siluf_(float x){ return x * sigmoidf_(x); }

// async global->LDS, 16B per lane; LDS dest = wave-uniform base + lane*16
__device__ __forceinline__ void gl16(const bf* g, bf* l) {
  __builtin_amdgcn_global_load_lds(
      (const __attribute__((address_space(1))) void*)g,
      (__attribute__((address_space(3))) void*)l, 16, 0, 0);
}

// ---------------- fp32 tiled GEMM (fc1, dtproj):  C[m,n] = sum_k A[m,k]*W[n,k] ----------------
// EPI: 0 = store, 2 = +bias, 3 = softplus(x+bias)
template<int BM, int BN, int EPI>
__global__ __launch_bounds__(256) void gemm_k(const float* __restrict__ A,
    const float* __restrict__ W, const float* __restrict__ bias,
    float* __restrict__ C, int M, int N, int K, int lda, int ldw, int ldc)
{
  constexpr int BK = 16;
  constexpr int TX = BN/4;
  constexpr int TY = 256/TX;
  constexpr int TM = BM/TY;
  __shared__ float As[BK][BM];
  __shared__ float Ws[BK][BN];
  const int t = threadIdx.x;
  const int n0 = blockIdx.x*BN, m0 = blockIdx.y*BM;
  const int tx = t % TX, ty = t / TX;
  float acc[TM][4];
  #pragma unroll
  for (int i=0;i<TM;i++){ acc[i][0]=0.f;acc[i][1]=0.f;acc[i][2]=0.f;acc[i][3]=0.f; }

  for (int k0=0;k0<K;k0+=BK) {
    __syncthreads();
    for (int f=t; f<BM*4; f+=256) {
      int row=f>>2, kq=f&3;
      float4 v = *(const float4*)(A + (size_t)(m0+row)*lda + (k0+kq*4));
      As[kq*4+0][row]=v.x; As[kq*4+1][row]=v.y; As[kq*4+2][row]=v.z; As[kq*4+3][row]=v.w;
    }
    for (int f=t; f<BN*4; f+=256) {
      int row=f>>2, kq=f&3;
      float4 v = *(const float4*)(W + (size_t)(n0+row)*ldw + (k0+kq*4));
      Ws[kq*4+0][row]=v.x; Ws[kq*4+1][row]=v.y; Ws[kq*4+2][row]=v.z; Ws[kq*4+3][row]=v.w;
    }
    __syncthreads();
    #pragma unroll
    for (int kk=0;kk<BK;kk++) {
      float a[TM], b[4];
      #pragma unroll
      for (int j=0;j<4;j++) b[j] = Ws[kk][tx*4+j];
      #pragma unroll
      for (int i=0;i<TM;i++) a[i] = As[kk][ty*TM+i];
      #pragma unroll
      for (int i=0;i<TM;i++)
        #pragma unroll
        for (int j=0;j<4;j++) acc[i][j] = fmaf(a[i], b[j], acc[i][j]);
    }
  }
  #pragma unroll
  for (int i=0;i<TM;i++) {
    float* cp = C + (size_t)(m0+ty*TM+i)*ldc + n0 + tx*4;
    float4 r; r.x=acc[i][0]; r.y=acc[i][1]; r.z=acc[i][2]; r.w=acc[i][3];
    if constexpr (EPI==2) { const float* bp = bias + n0 + tx*4;
      r.x+=bp[0]; r.y+=bp[1]; r.z+=bp[2]; r.w+=bp[3]; }
    if constexpr (EPI==3) { const float* bp = bias + n0 + tx*4;
      r.x=softplusf_(r.x+bp[0]); r.y=softplusf_(r.y+bp[1]);
      r.z=softplusf_(r.z+bp[2]); r.w=softplusf_(r.w+bp[3]); }
    *(float4*)cp = r;
  }
}

// ------- split-bf16 MFMA GEMM v3: double-buffered gl_lds 2-phase pipeline -------
// C[m,n] (+)= sum_k A[m,k]*W[n,k];  cols < nsplit -> Cx, cols >= nsplit -> Cz (col-nsplit)
// EPI: 0 = store, 1 = accumulate. Requires grid blocks % 8 == 0, K % 32 == 0.
template<int BM, int BN, int WR, int WC, int EPI>
__global__ __launch_bounds__(256) void gemm_mfma2_k(
    const bf* __restrict__ Ahi, const bf* __restrict__ Alo,
    const bf* __restrict__ Whi, const bf* __restrict__ Wlo,
    float* __restrict__ Cx, float* __restrict__ Cz, int nsplit,
    int M, int N, int K, int ldc)
{
  constexpr int WM = BM/WR, WN = BN/WC;
  constexpr int FM = WM/16, FN = WN/16;
  __shared__ bf sAh[2][BM*32], sAl[2][BM*32], sWh[2][BN*32], sWl[2][BN*32];
  const int t = threadIdx.x;
  const int w = t>>6, lane = t&63;
  const int wr = w%WR, wc = w/WR;
  const int lr = lane&15, lk = lane>>4;
  const int rowl = lane>>2, coll = (lane&3)*8;

  // bijective XCD swizzle: each XCD gets a contiguous chunk of logical tiles
  const int gx = gridDim.x;
  const int flat = blockIdx.y*gx + blockIdx.x;
  const int cpx = (gx*gridDim.y)>>3;
  const int logical = (flat&7)*cpx + (flat>>3);
  const int m0 = (logical/gx)*BM, n0 = (logical%gx)*BN;

  fx4 acc[FM][FN];
  #pragma unroll
  for (int i=0;i<FM;i++)
    #pragma unroll
    for (int j=0;j<FN;j++) acc[i][j] = fx4{0.f,0.f,0.f,0.f};

  auto stage = [&](int buf, int k0) {
    {
      const int rb = w*(BM/4);
      #pragma unroll
      for (int q=0;q<BM/64;q++) {
        int r = rb + q*16 + rowl;
        size_t g = (size_t)(m0+r)*K + k0 + coll;
        gl16(Ahi+g, &sAh[buf][(rb+q*16)*32]);
        gl16(Alo+g, &sAl[buf][(rb+q*16)*32]);
      }
    }
    {
      const int rb = w*(BN/4);
      #pragma unroll
      for (int q=0;q<BN/64;q++) {
        int r = rb + q*16 + rowl;
        size_t g = (size_t)(n0+r)*K + k0 + coll;
        gl16(Whi+g, &sWh[buf][(rb+q*16)*32]);
        gl16(Wlo+g, &sWl[buf][(rb+q*16)*32]);
      }
    }
  };

  const int NT = K/32;
  stage(0, 0);
  __syncthreads();                     // drain: buf0 ready
  int cur = 0;
  for (int tt=0; tt<NT; ++tt) {
    if (tt+1 < NT) stage(cur^1, (tt+1)*32);   // issue next tile BEFORE compute
    bx8 ah[FM], al[FM], bh[FN], bl[FN];
    #pragma unroll
    for (int i=0;i<FM;i++) {
      int row = wr*WM + i*16 + lr;
      ah[i] = *(const bx8*)&sAh[cur][row*32 + lk*8];
      al[i] = *(const bx8*)&sAl[cur][row*32 + lk*8];
    }
    #pragma unroll
    for (int j=0;j<FN;j++) {
      int row = wc*WN + j*16 + lr;
      bh[j] = *(const bx8*)&sWh[cur][row*32 + lk*8];
      bl[j] = *(const bx8*)&sWl[cur][row*32 + lk*8];
    }
    #pragma unroll
    for (int i=0;i<FM;i++)
      #pragma unroll
      for (int j=0;j<FN;j++) {
        acc[i][j] = __builtin_amdgcn_mfma_f32_16x16x32_bf16(ah[i], bh[j], acc[i][j], 0,0,0);
        acc[i][j] = __builtin_amdgcn_mfma_f32_16x16x32_bf16(ah[i], bl[j], acc[i][j], 0,0,0);
        acc[i][j] = __builtin_amdgcn_mfma_f32_16x16x32_bf16(al[i], bh[j], acc[i][j], 0,0,0);
      }
    __syncthreads();                  // drains stage(cur^1); all reads of cur done
    cur ^= 1;
  }
  #pragma unroll
  for (int j=0;j<FN;j++) {
    int coln = n0 + wc*WN + j*16 + lr;
    float* Cb; int cc;
    if (coln < nsplit) { Cb = Cx; cc = coln; } else { Cb = Cz; cc = coln - nsplit; }
    #pragma unroll
    for (int i=0;i<FM;i++) {
      #pragma unroll
      for (int r=0;r<4;r++) {
        int row = m0 + wr*WM + i*16 + lk*4 + r;
        if constexpr (EPI==1) Cb[(size_t)row*ldc+cc] += acc[i][j][r];
        else                  Cb[(size_t)row*ldc+cc]  = acc[i][j][r];
      }
    }
  }
}

// ---------------- fused per-layer prep: rmsnorm | split(in_w) | split(out_w) | wtrans ----------------
__device__ __forceinline__ void split4_(const float* __restrict__ in,
    bf* __restrict__ hi, bf* __restrict__ lo, int i)
{
  float4 v = ((const float4*)in)[i];
  float f[4] = {v.x, v.y, v.z, v.w};
  bf hh[4], ll[4];
  #pragma unroll
  for (int j=0;j<4;j++) {
    hh[j] = __float2bfloat16(f[j]);
    ll[j] = __float2bfloat16(f[j] - __bfloat162float(hh[j]));
  }
  *(float2*)(hi + 4*(size_t)i) = *(float2*)hh;
  *(float2*)(lo + 4*(size_t)i) = *(float2*)ll;
}

__global__ __launch_bounds__(256) void prep_k(
    const float* __restrict__ h, const float* __restrict__ nw,
    bf* __restrict__ hn_hi, bf* __restrict__ hn_lo,
    const float* __restrict__ in_w, bf* __restrict__ win_hi, bf* __restrict__ win_lo,
    const float* __restrict__ out_w, bf* __restrict__ wout_hi, bf* __restrict__ wout_lo,
    const float* __restrict__ xw, float* __restrict__ Wt)
{
  __shared__ float smem[64*65];
  const int bid = blockIdx.x, t = threadIdx.x;
  if (bid < 4096) {                          // rmsnorm row
    const float* row = h + (size_t)bid*DM;
    float v0 = row[t], v1 = row[t+256];
    float s = v0*v0 + v1*v1;
    #pragma unroll
    for (int off=32; off>=1; off>>=1) s += __shfl_xor(s, off, 64);
    if ((t&63)==0) smem[t>>6] = s;
    __syncthreads();
    float tot = smem[0]+smem[1]+smem[2]+smem[3];
    float r = rsqrtf(tot*(1.0f/512.0f) + 1e-5f);
    float o0 = v0*r*nw[t], o1 = v1*r*nw[t+256];
    bf h0 = __float2bfloat16(o0), h1 = __float2bfloat16(o1);
    hn_hi[(size_t)bid*DM+t]     = h0;
    hn_lo[(size_t)bid*DM+t]     = __float2bfloat16(o0 - __bfloat162float(h0));
    hn_hi[(size_t)bid*DM+t+256] = h1;
    hn_lo[(size_t)bid*DM+t+256] = __float2bfloat16(o1 - __bfloat162float(h1));
  } else if (bid < 5120) {                   // split in_proj_w (262144 float4s)
    split4_(in_w, win_hi, win_lo, (bid-4096)*256 + t);
  } else if (bid < 5632) {                   // split out_proj_w (131072 float4s)
    split4_(out_w, wout_hi, wout_lo, (bid-5120)*256 + t);
  } else {                                   // wtrans: 16 k-tiles of 64
    float (*tile)[65] = (float(*)[65])smem;
    const int kb = bid - 5632;
    for (int i=t; i<4096; i+=256) {
      int n = i>>6, c = i&63;
      tile[n][c] = xw[(size_t)n*EDIM + kb*64 + c];
    }
    __syncthreads();
    for (int i=t; i<4096; i+=256) {
      int kk = i>>6, n = i&63;
      Wt[((size_t)kb*64+kk)*64 + n] = tile[n][kk];
    }
  }
}

// ---------------- causal depthwise conv (K=4) + silu; reads contiguous Xb ----------------
__global__ __launch_bounds__(256) void conv_silu_k(const float* __restrict__ Xb,
    const float* __restrict__ cw, const float* __restrict__ cb, float* __restrict__ xbc)
{
  int idx = blockIdx.x*256 + threadIdx.x;
  int e = idx & (EDIM-1);
  int m = idx >> 10;
  int l = m & (LSEQ-1);
  float4 w = *(const float4*)(cw + e*4);
  const float* xp = Xb + (size_t)m*EDIM + e;
  float acc = cb[e] + w.w * xp[0];
  if (l>0) acc += w.z * xp[-EDIM];
  if (l>1) acc += w.y * xp[-2*EDIM];
  if (l>2) acc += w.x * xp[-3*EDIM];
  xbc[idx] = siluf_(acc);
}

// ---------------- xproj split-K partials: Cp[kc][m][n], kc = K/256 chunk ----------------
__global__ __launch_bounds__(256) void xproj_part_k(const float* __restrict__ A,
    const float* __restrict__ Wt, float* __restrict__ Cp)
{
  constexpr int KC = 256;
  __shared__ float As[16][KC];          // 16 KB
  const int mb = blockIdx.x;            // 256 m-tiles of 16 rows
  const int kc = blockIdx.y;            // 4 k-chunks
  const int t  = threadIdx.x;
  const float* ap = A + ((size_t)mb*16)*EDIM + kc*KC;
  #pragma unroll
  for (int q=0;q<4;q++) {               // 1024 float4 loads / 256 threads
    int i = q*256 + t;
    int r = i>>6, c4 = i&63;
    float4 v = *(const float4*)(ap + (size_t)r*EDIM + c4*4);
    *(float4*)&As[r][c4*4] = v;
  }
  __syncthreads();
  const int m = t>>4, n0 = (t&15)*4;
  const float* wp = Wt + (size_t)kc*KC*64 + n0;
  float4 acc = {0.f,0.f,0.f,0.f};
  #pragma unroll 8
  for (int k=0;k<KC;k++) {
    float a = As[m][k];
    float4 w = *(const float4*)(wp + (size_t)k*64);
    acc.x = fmaf(a,w.x,acc.x); acc.y = fmaf(a,w.y,acc.y);
    acc.z = fmaf(a,w.z,acc.z); acc.w = fmaf(a,w.w,acc.w);
  }
  *(float4*)(Cp + ((size_t)kc*MTOK + (size_t)mb*16 + m)*64 + n0) = acc;
}

// ---------------- xproj reduce: C[m][n] = sum_kc Cp[kc][m][n] ----------------
__global__ __launch_bounds__(256) void xproj_red_k(const float* __restrict__ Cp,
    float* __restrict__ C)
{
  int i = blockIdx.x*256 + threadIdx.x;        // 65536 float4 slots
  const size_t stride = (size_t)MTOK*64/4;
  float4 a = ((const float4*)Cp)[i];
  float4 b = ((const float4*)Cp)[i + stride];
  float4 c = ((const float4*)Cp)[i + 2*stride];
  float4 d = ((const float4*)Cp)[i + 3*stride];
  float4 r; r.x=a.x+b.x+c.x+d.x; r.y=a.y+b.y+c.y+d.y;
  r.z=a.z+b.z+c.z+d.z; r.w=a.w+b.w+c.w+d.w;
  ((float4*)C)[i] = r;
}

// ---------------- chunked selective scan (NC=32, CH=32), full register preload ----------------
// P/S/Hinit layout: [b][c][n][ed]
__global__ __launch_bounds__(256,2) void scan_chunkA_k(const float* __restrict__ xbc,
    const float* __restrict__ dl, const float* __restrict__ dbc,
    const float* __restrict__ A_log,
    float* __restrict__ P, float* __restrict__ S)
{
  int ed = blockIdx.x*256 + threadIdx.x;
  int b = blockIdx.y, c = blockIdx.z;
  const int l0 = c*CH;
  __shared__ float Bs[CH][NST];
  for (int i=threadIdx.x; i<CH*NST; i+=256) {
    int row = i>>4, col = i&15;
    Bs[row][col] = dbc[((size_t)b*LSEQ + l0 + row)*64 + 32 + col];
  }
  __syncthreads();
  const float* dp = dl  + ((size_t)b*LSEQ + l0)*EDIM + ed;
  const float* xp = xbc + ((size_t)b*LSEQ + l0)*EDIM + ed;
  float dt[CH], xv[CH];
  #pragma unroll
  for (int l=0;l<CH;l++){ dt[l]=dp[(size_t)l*EDIM]; xv[l]=xp[(size_t)l*EDIM]; }
  float a[NST], hs[NST], pp[NST];
  #pragma unroll
  for (int n=0;n<NST;n++){ a[n] = -__expf(A_log[ed*NST+n]); hs[n]=0.f; pp[n]=1.f; }
  #pragma unroll
  for (int l=0;l<CH;l++) {
    float dx = dt[l]*xv[l];
    #pragma unroll
    for (int n=0;n<NST;n++) {
      float dA = __expf(dt[l]*a[n]);
      hs[n] = fmaf(dA, hs[n], dx*Bs[l][n]);
      pp[n] *= dA;
    }
  }
  size_t base = (((size_t)b*NC + c)*NST)*EDIM + ed;
  #pragma unroll
  for (int n=0;n<NST;n++) { P[base + (size_t)n*EDIM] = pp[n]; S[base + (size_t)n*EDIM] = hs[n]; }
}

__global__ __launch_bounds__(256) void scan_combine_k(float* __restrict__ PH, const float* __restrict__ S)
{
  int t = blockIdx.x*256 + threadIdx.x;       // n*EDIM+ed
  int b = blockIdx.y;
  const size_t stride = (size_t)NST*EDIM;
  size_t b0 = (size_t)b*NC*stride + t;
  float p[NC], s[NC];
  #pragma unroll
  for (int c=0;c<NC;c++){ p[c]=PH[b0+(size_t)c*stride]; s[c]=S[b0+(size_t)c*stride]; }
  float H = 0.f;
  #pragma unroll
  for (int c=0;c<NC;c++){ PH[b0+(size_t)c*stride] = H; H = fmaf(p[c], H, s[c]); }
}

// Pass C: replay from true init; fused y*silu(z); emits bf16 hi/lo.
__global__ __launch_bounds__(256,2) void scan_chunkC_k(const float* __restrict__ xbc,
    const float* __restrict__ dl, const float* __restrict__ dbc,
    const float* __restrict__ A_log, const float* __restrict__ Dp,
    const float* __restrict__ Hinit, const float* __restrict__ Z,
    bf* __restrict__ yz_hi, bf* __restrict__ yz_lo)
{
  int ed = blockIdx.x*256 + threadIdx.x;
  int b = blockIdx.y, c = blockIdx.z;
  const int l0 = c*CH;
  __shared__ float BCs[CH][32];
  for (int i=threadIdx.x; i<CH*32; i+=256) {
    int row = i>>5, col = i&31;
    BCs[row][col] = dbc[((size_t)b*LSEQ + l0 + row)*64 + 32 + col];
  }
  __syncthreads();
  const float* dp = dl  + ((size_t)b*LSEQ + l0)*EDIM + ed;
  const float* xp = xbc + ((size_t)b*LSEQ + l0)*EDIM + ed;
  const float* zp = Z   + ((size_t)b*LSEQ + l0)*EDIM + ed;
  float dt[CH], xv[CH], zv[CH];
  #pragma unroll
  for (int l=0;l<CH;l++){ dt[l]=dp[(size_t)l*EDIM]; xv[l]=xp[(size_t)l*EDIM]; zv[l]=zp[(size_t)l*EDIM]; }
  float a[NST], hs[NST];
  size_t base = (((size_t)b*NC + c)*NST)*EDIM + ed;
  #pragma unroll
  for (int n=0;n<NST;n++){ a[n] = -__expf(A_log[ed*NST+n]); hs[n] = Hinit[base + (size_t)n*EDIM]; }
  float Dv = Dp[ed];
  bf* yh = yz_hi + ((size_t)b*LSEQ + l0)*EDIM + ed;
  bf* yl = yz_lo + ((size_t)b*LSEQ + l0)*EDIM + ed;
  #pragma unroll
  for (int l=0;l<CH;l++) {
    float dx = dt[l]*xv[l];
    float yv = xv[l]*Dv;
    #pragma unroll
    for (int n=0;n<NST;n++) {
      float dA = __expf(dt[l]*a[n]);
      hs[n] = fmaf(dA, hs[n], dx*BCs[l][n]);
      yv = fmaf(hs[n], BCs[l][16+n], yv);
    }
    float g = yv * siluf_(zv[l]);
    bf gh = __float2bfloat16(g);
    yh[(size_t)l*EDIM] = gh;
    yl[(size_t)l*EDIM] = __float2bfloat16(g - __bfloat162float(gh));
  }
}

// ---------------- fc2 (D=512 -> 1) + sigmoid ----------------
__global__ __launch_bounds__(64) void fc2_k(const float* __restrict__ h,
    const float* __restrict__ w, const float* __restrict__ b, float* __restrict__ out)
{
  int m = blockIdx.x, t = threadIdx.x;
  float s = 0.f;
  #pragma unroll
  for (int j=0;j<8;j++) { int k = t + j*64; s = fmaf(h[(size_t)m*DM+k], w[k], s); }
  #pragma unroll
  for (int off=32; off>=1; off>>=1) s += __shfl_xor(s, off, 64);
  if (t==0) out[m] = sigmoidf_(s + b[0]);
}

extern "C" void kernel_launch(void* const* d_in, const int* in_sizes, int n_in,
                              void* d_out, int out_size, void* d_ws, size_t ws_size,
                              hipStream_t stream) {
  const float* x         = (const float*)d_in[0];
  const float* fc1_w     = (const float*)d_in[1];
  const float* fc1_b     = (const float*)d_in[2];
  const float* fc2_w     = (const float*)d_in[3];
  const float* fc2_b     = (const float*)d_in[4];
  const float* norm_w    = (const float*)d_in[5];
  const float* in_proj_w = (const float*)d_in[6];
  const float* conv_w    = (const float*)d_in[7];
  const float* conv_b    = (const float*)d_in[8];
  const float* xproj_w   = (const float*)d_in[9];
  const float* dtproj_w  = (const float*)d_in[10];
  const float* dtproj_b  = (const float*)d_in[11];
  const float* A_log     = (const float*)d_in[12];
  const float* D_param   = (const float*)d_in[13];
  const float* out_proj_w= (const float*)d_in[14];
  float* out = (float*)d_out;

  char* w8 = (char*)d_ws;                  // total footprint: 104 MB (<=105 proven)
  float* h    = (float*)(w8 +  0*MB);      //  8 MB
  float* Xb   = (float*)(w8 +  8*MB);      // 16 MB (dead after conv)
  float* PH   = (float*)(w8 +  8*MB);      //  8 MB (alias Xb; live scanA..scanC)
  float* Z    = (float*)(w8 + 24*MB);      // 16 MB (live till scanC)
  float* xbc  = (float*)(w8 + 40*MB);      // 16 MB
  float* dl   = (float*)(w8 + 56*MB);      // 16 MB
  float* dbcw = (float*)(w8 + 72*MB);      //  1 MB
  bf*    win_hi = (bf*)(w8 + 73*MB);       //  2 MB (dead after in_proj)
  bf*    win_lo = (bf*)(w8 + 75*MB);       //  2 MB
  bf*    wout_hi= (bf*)(w8 + 77*MB);       //  1 MB
  bf*    wout_lo= (bf*)(w8 + 78*MB);       //  1 MB
  bf*    hn_hi  = (bf*)(w8 + 79*MB);       //  4 MB (dead after in_proj)
  bf*    hn_lo  = (bf*)(w8 + 83*MB);       //  4 MB
  float* Send   = (float*)(w8 + 79*MB);    //  8 MB (alias hn; live scanA..combine)
  float* Cp     = (float*)(w8 + 79*MB);    //  4 MB (alias hn; live xproj_part..red, before Send)
  bf*    yz_hi  = (bf*)(w8 + 87*MB);       //  8 MB
  bf*    yz_lo  = (bf*)(w8 + 95*MB);       //  8 MB
  float* Wt     = (float*)(w8 + 103*MB);   //  256 KB (own slot: written by prep while win live)

  // fc1: h = x @ fc1_w^T + fc1_b    (4096 x 512, K=32)
  gemm_k<128,64,2><<<dim3(DM/64, MTOK/128), 256, 0, stream>>>(
      x, fc1_w, fc1_b, h, MTOK, DM, DIN, DIN, DIN, DM);

  for (int i=0;i<4;i++) {
    // fused prep: rmsnorm | split(in_w) | split(out_w) | wtrans
    prep_k<<<5648, 256, 0, stream>>>(
        h, norm_w + (size_t)i*DM, hn_hi, hn_lo,
        in_proj_w + (size_t)i*2048*DM, win_hi, win_lo,
        out_proj_w + (size_t)i*DM*EDIM, wout_hi, wout_lo,
        xproj_w + (size_t)i*64*EDIM, Wt);
    // in_proj merged: N=2048, cols<1024 -> Xb, cols>=1024 -> Z  (512 blocks, 2/CU)
    gemm_mfma2_k<128,128,2,2,0><<<dim3(2048/128, MTOK/128), 256, 0, stream>>>(
        hn_hi, hn_lo, win_hi, win_lo, Xb, Z, 1024, MTOK, 2048, DM, EDIM);
    conv_silu_k<<<(MTOK*EDIM)/256, 256, 0, stream>>>(
        Xb, conv_w + (size_t)i*EDIM*4, conv_b + (size_t)i*EDIM, xbc);
    // xproj: split-K partials (1024 blocks), reduce
    xproj_part_k<<<dim3(MTOK/16, 4), 256, 0, stream>>>(xbc, Wt, Cp);
    xproj_red_k<<<(MTOK*64/4)/256, 256, 0, stream>>>(Cp, dbcw);
    // delta = softplus(dt @ dtproj_w^T + dtproj_b)   (4096 x 1024, K=32, lda=64)
    gemm_k<128,64,3><<<dim3(EDIM/64, MTOK/128), 256, 0, stream>>>(
        dbcw, dtproj_w + (size_t)i*EDIM*RANK, dtproj_b + (size_t)i*EDIM, dl,
        MTOK, EDIM, RANK, 64, RANK, EDIM);
    // chunked selective scan
    scan_chunkA_k<<<dim3(EDIM/256, BB, NC), 256, 0, stream>>>(
        xbc, dl, dbcw, A_log + (size_t)i*EDIM*NST, PH, Send);
    scan_combine_k<<<dim3(NST*EDIM/256, BB), 256, 0, stream>>>(PH, Send);
    scan_chunkC_k<<<dim3(EDIM/256, BB, NC), 256, 0, stream>>>(
        xbc, dl, dbcw, A_log + (size_t)i*EDIM*NST, D_param + (size_t)i*EDIM, PH,
        Z, yz_hi, yz_lo);
    // h += yz @ out_proj_w^T  (4096 x 512, K=1024)  [64x64 tiles, 512 blocks]
    gemm_mfma2_k<64,64,2,2,1><<<dim3(DM/64, MTOK/64), 256, 0, stream>>>(
        yz_hi, yz_lo, wout_hi, wout_lo, h, h, DM, MTOK, DM, EDIM, DM);
  }

  // out = sigmoid(h @ fc2_w^T + fc2_b)
  fc2_k<<<MTOK, 64, 0, stream>>>(h, fc2_w, fc2_b, out);
}